// Round 1
// baseline (614.223 us; speedup 1.0000x reference)
//
#include <hip/hip_runtime.h>
#include <math.h>

#define NB   8
#define NN   8192
#define NS   2048
#define ND1  128
#define ND2  256
#define NCIN 384
#define NC1  256
#define NC2  128

#define EPS_ITP 1e-8f
#define EPS_INORM 1e-5f

// ---------------------------------------------------------------------------
// Kernel 1: 3-NN + inverse-distance interpolation + concat -> x [B][N][384]
// One block = 256 points of one batch. xyz2[b] staged in LDS as (x,y,z,|q|^2).
// ---------------------------------------------------------------------------
__global__ __launch_bounds__(256) void k_knn_interp(
    const float* __restrict__ xyz1, const float* __restrict__ xyz2,
    const float* __restrict__ points1, const float* __restrict__ points2,
    float* __restrict__ x)
{
    __shared__ float q[NS * 4];
    __shared__ int   si[256][3];
    __shared__ float sw[256][3];
    const int t  = threadIdx.x;
    const int b  = blockIdx.y;
    const int n0 = blockIdx.x * 256;

    const float* xz2 = xyz2 + b * NS * 3;
    for (int e = t; e < NS * 3; e += 256)
        q[(e / 3) * 4 + (e % 3)] = xz2[e];
    __syncthreads();
    for (int s = t; s < NS; s += 256) {
        float qx = q[s*4+0], qy = q[s*4+1], qz = q[s*4+2];
        q[s*4+3] = qx*qx + qy*qy + qz*qz;
    }
    __syncthreads();

    const int n = n0 + t;
    const float px = xyz1[(b*NN + n)*3 + 0];
    const float py = xyz1[(b*NN + n)*3 + 1];
    const float pz = xyz1[(b*NN + n)*3 + 2];
    const float p2 = px*px + py*py + pz*pz;

    // top-3 smallest d = |p|^2 + |q|^2 - 2 p.q  (matches reference formula)
    float d0 = 3.4e38f, d1 = 3.4e38f, d2 = 3.4e38f;
    int   i0 = 0, i1 = 0, i2 = 0;
    for (int s = 0; s < NS; ++s) {
        float4 qq = *(const float4*)&q[s*4];
        float dot = px*qq.x + py*qq.y + pz*qq.z;
        float d = p2 + qq.w - 2.0f*dot;
        if (d < d2) {
            if (d < d1) {
                if (d < d0) { d2=d1; i2=i1; d1=d0; i1=i0; d0=d; i0=s; }
                else        { d2=d1; i2=i1; d1=d;  i1=s; }
            } else          { d2=d;  i2=s; }
        }
    }
    {
        float r0 = 1.0f/(d0+EPS_ITP), r1 = 1.0f/(d1+EPS_ITP), r2 = 1.0f/(d2+EPS_ITP);
        float rsum = r0 + r1 + r2;
        sw[t][0] = r0/rsum; sw[t][1] = r1/rsum; sw[t][2] = r2/rsum;
        si[t][0] = i0; si[t][1] = i1; si[t][2] = i2;
    }
    __syncthreads();

    // copy points1 -> x[:, 0:128]   (coalesced: lane -> channel)
    const float* p1 = points1 + (size_t)(b*NN + n0) * ND1;
    float* xb = x + (size_t)(b*NN + n0) * NCIN;
    const int cp = t & 127;
    const int ph = t >> 7;
    for (int i = 0; i < 128; ++i) {
        int p = i*2 + ph;
        xb[(size_t)p*NCIN + cp] = p1[p*ND1 + cp];
    }
    // interpolate -> x[:, 128:384]  (lane = channel, rows gathered, coalesced 1KB)
    const float* p2b = points2 + (size_t)b*NS*ND2;
    for (int j = 0; j < 256; ++j) {
        float w0 = sw[j][0], w1 = sw[j][1], w2 = sw[j][2];
        int   a0 = si[j][0], a1 = si[j][1], a2 = si[j][2];
        float v = w0*p2b[a0*ND2 + t] + w1*p2b[a1*ND2 + t] + w2*p2b[a2*ND2 + t];
        xb[(size_t)j*NCIN + ND1 + t] = v;
    }
}

// ---------------------------------------------------------------------------
// GEMM1: y1[b][o][n] = b1[o] + sum_c W1[o][c] * x[b][n][c]
// block tile 64(o) x 128(n), BK=32, micro-tile 4x8 per thread.
// As[k][o] stride 68, Bs[k][n] stride 132 (bank-conflict-free mappings).
// ---------------------------------------------------------------------------
__global__ __launch_bounds__(256) void k_gemm1(
    const float* __restrict__ x, const float* __restrict__ W1,
    const float* __restrict__ b1, float* __restrict__ y1)
{
    __shared__ float As[32*68];
    __shared__ float Bs[32*132];
    const int t  = threadIdx.x;
    const int n1 = blockIdx.x * 128;
    const int o1 = blockIdx.y * 64;
    const int b  = blockIdx.z;

    const float* xb = x + (size_t)b*NN*NCIN;
    float acc[4][8];
    #pragma unroll
    for (int i = 0; i < 4; ++i)
        #pragma unroll
        for (int j = 0; j < 8; ++j) acc[i][j] = 0.f;

    const int og = (t>>4)<<2;
    const int ng = (t&15)<<3;
    const int ao = t>>2, ak = (t&3)<<3;   // A-stage: row o1+ao, cols k0+ak..+7
    const int bn = t>>1, bk = (t&1)<<4;   // B-stage: row n1+bn, cols k0+bk..+15

    const float* asrc = W1 + (size_t)(o1+ao)*NCIN + ak;
    const float* bsrc = xb + (size_t)(n1+bn)*NCIN + bk;

    for (int k0 = 0; k0 < NCIN; k0 += 32) {
        float4 a0 = *(const float4*)(asrc + k0);
        float4 a1 = *(const float4*)(asrc + k0 + 4);
        float4 v0 = *(const float4*)(bsrc + k0);
        float4 v1 = *(const float4*)(bsrc + k0 + 4);
        float4 v2 = *(const float4*)(bsrc + k0 + 8);
        float4 v3 = *(const float4*)(bsrc + k0 + 12);
        As[(ak+0)*68+ao] = a0.x; As[(ak+1)*68+ao] = a0.y;
        As[(ak+2)*68+ao] = a0.z; As[(ak+3)*68+ao] = a0.w;
        As[(ak+4)*68+ao] = a1.x; As[(ak+5)*68+ao] = a1.y;
        As[(ak+6)*68+ao] = a1.z; As[(ak+7)*68+ao] = a1.w;
        Bs[(bk+ 0)*132+bn] = v0.x; Bs[(bk+ 1)*132+bn] = v0.y;
        Bs[(bk+ 2)*132+bn] = v0.z; Bs[(bk+ 3)*132+bn] = v0.w;
        Bs[(bk+ 4)*132+bn] = v1.x; Bs[(bk+ 5)*132+bn] = v1.y;
        Bs[(bk+ 6)*132+bn] = v1.z; Bs[(bk+ 7)*132+bn] = v1.w;
        Bs[(bk+ 8)*132+bn] = v2.x; Bs[(bk+ 9)*132+bn] = v2.y;
        Bs[(bk+10)*132+bn] = v2.z; Bs[(bk+11)*132+bn] = v2.w;
        Bs[(bk+12)*132+bn] = v3.x; Bs[(bk+13)*132+bn] = v3.y;
        Bs[(bk+14)*132+bn] = v3.z; Bs[(bk+15)*132+bn] = v3.w;
        __syncthreads();
        #pragma unroll 8
        for (int k = 0; k < 32; ++k) {
            float4 aa = *(const float4*)&As[k*68 + og];
            float4 b0 = *(const float4*)&Bs[k*132 + ng];
            float4 b1v = *(const float4*)&Bs[k*132 + ng + 4];
            float ar[4] = {aa.x, aa.y, aa.z, aa.w};
            float br[8] = {b0.x, b0.y, b0.z, b0.w, b1v.x, b1v.y, b1v.z, b1v.w};
            #pragma unroll
            for (int i = 0; i < 4; ++i)
                #pragma unroll
                for (int j = 0; j < 8; ++j)
                    acc[i][j] = fmaf(ar[i], br[j], acc[i][j]);
        }
        __syncthreads();
    }

    float* yb = y1 + ((size_t)b*NC1 + o1)*NN + n1;
    #pragma unroll
    for (int i = 0; i < 4; ++i) {
        float bias = b1[o1 + og + i];
        float4 w0 = make_float4(acc[i][0]+bias, acc[i][1]+bias, acc[i][2]+bias, acc[i][3]+bias);
        float4 w1 = make_float4(acc[i][4]+bias, acc[i][5]+bias, acc[i][6]+bias, acc[i][7]+bias);
        *(float4*)(yb + (size_t)(og+i)*NN + ng)     = w0;
        *(float4*)(yb + (size_t)(og+i)*NN + ng + 4) = w1;
    }
}

// ---------------------------------------------------------------------------
// Row stats: mean + 1/sqrt(var+eps) per row of length NN (biased var).
// ---------------------------------------------------------------------------
__global__ __launch_bounds__(256) void k_rowstats(
    const float* __restrict__ y, float* __restrict__ mu, float* __restrict__ rs)
{
    const int row = blockIdx.x;
    const float4* p = (const float4*)(y + (size_t)row * NN);
    float s = 0.f, s2 = 0.f;
    for (int i = threadIdx.x; i < NN/4; i += 256) {
        float4 v = p[i];
        s  += v.x + v.y + v.z + v.w;
        s2 += v.x*v.x + v.y*v.y + v.z*v.z + v.w*v.w;
    }
    #pragma unroll
    for (int off = 32; off > 0; off >>= 1) {
        s  += __shfl_down(s,  off, 64);
        s2 += __shfl_down(s2, off, 64);
    }
    __shared__ float ls[4], ls2[4];
    const int wid  = threadIdx.x >> 6;
    const int lane = threadIdx.x & 63;
    if (lane == 0) { ls[wid] = s; ls2[wid] = s2; }
    __syncthreads();
    if (threadIdx.x == 0) {
        float S  = ls[0]+ls[1]+ls[2]+ls[3];
        float S2 = ls2[0]+ls2[1]+ls2[2]+ls2[3];
        float m  = S / (float)NN;
        float var = S2 / (float)NN - m*m;
        mu[row] = m;
        rs[row] = 1.0f / sqrtf(var + EPS_INORM);
    }
}

// ---------------------------------------------------------------------------
// GEMM2: y2[b][o][n] = b2[o] + sum_c W2[o][c] * relu((y1[b][c][n]-mu1)*rs1)
// Same tiling as GEMM1; normalization applied while staging B.
// ---------------------------------------------------------------------------
__global__ __launch_bounds__(256) void k_gemm2(
    const float* __restrict__ y1, const float* __restrict__ W2,
    const float* __restrict__ b2, const float* __restrict__ mu1,
    const float* __restrict__ rs1, float* __restrict__ y2)
{
    __shared__ float As[32*68];
    __shared__ float Bs[32*132];
    const int t  = threadIdx.x;
    const int n1 = blockIdx.x * 128;
    const int o1 = blockIdx.y * 64;
    const int b  = blockIdx.z;

    const float* yb1 = y1 + (size_t)b*NC1*NN;
    float acc[4][8];
    #pragma unroll
    for (int i = 0; i < 4; ++i)
        #pragma unroll
        for (int j = 0; j < 8; ++j) acc[i][j] = 0.f;

    const int og = (t>>4)<<2;
    const int ng = (t&15)<<3;
    const int ao = t>>2, ak = (t&3)<<3;     // A-stage from W2 [128][256]
    const int bkr = t>>3;                   // B-stage: k row (0..31)
    const int bnn = (t&7)<<4;               // cols n1+bnn..+15

    const float* asrc = W2 + (size_t)(o1+ao)*NC1 + ak;

    for (int k0 = 0; k0 < NC1; k0 += 32) {
        float4 a0 = *(const float4*)(asrc + k0);
        float4 a1 = *(const float4*)(asrc + k0 + 4);
        const float* bsrc = yb1 + (size_t)(k0 + bkr)*NN + n1 + bnn;
        float m = mu1[b*NC1 + k0 + bkr];
        float r = rs1[b*NC1 + k0 + bkr];
        float4 v0 = *(const float4*)(bsrc);
        float4 v1 = *(const float4*)(bsrc + 4);
        float4 v2 = *(const float4*)(bsrc + 8);
        float4 v3 = *(const float4*)(bsrc + 12);
        v0.x = fmaxf(0.f,(v0.x-m)*r); v0.y = fmaxf(0.f,(v0.y-m)*r);
        v0.z = fmaxf(0.f,(v0.z-m)*r); v0.w = fmaxf(0.f,(v0.w-m)*r);
        v1.x = fmaxf(0.f,(v1.x-m)*r); v1.y = fmaxf(0.f,(v1.y-m)*r);
        v1.z = fmaxf(0.f,(v1.z-m)*r); v1.w = fmaxf(0.f,(v1.w-m)*r);
        v2.x = fmaxf(0.f,(v2.x-m)*r); v2.y = fmaxf(0.f,(v2.y-m)*r);
        v2.z = fmaxf(0.f,(v2.z-m)*r); v2.w = fmaxf(0.f,(v2.w-m)*r);
        v3.x = fmaxf(0.f,(v3.x-m)*r); v3.y = fmaxf(0.f,(v3.y-m)*r);
        v3.z = fmaxf(0.f,(v3.z-m)*r); v3.w = fmaxf(0.f,(v3.w-m)*r);
        As[(ak+0)*68+ao] = a0.x; As[(ak+1)*68+ao] = a0.y;
        As[(ak+2)*68+ao] = a0.z; As[(ak+3)*68+ao] = a0.w;
        As[(ak+4)*68+ao] = a1.x; As[(ak+5)*68+ao] = a1.y;
        As[(ak+6)*68+ao] = a1.z; As[(ak+7)*68+ao] = a1.w;
        float* bd = &Bs[bkr*132 + bnn];
        bd[0]=v0.x; bd[1]=v0.y; bd[2]=v0.z; bd[3]=v0.w;
        bd[4]=v1.x; bd[5]=v1.y; bd[6]=v1.z; bd[7]=v1.w;
        bd[8]=v2.x; bd[9]=v2.y; bd[10]=v2.z; bd[11]=v2.w;
        bd[12]=v3.x; bd[13]=v3.y; bd[14]=v3.z; bd[15]=v3.w;
        __syncthreads();
        #pragma unroll 8
        for (int k = 0; k < 32; ++k) {
            float4 aa = *(const float4*)&As[k*68 + og];
            float4 b0 = *(const float4*)&Bs[k*132 + ng];
            float4 b1v = *(const float4*)&Bs[k*132 + ng + 4];
            float ar[4] = {aa.x, aa.y, aa.z, aa.w};
            float br[8] = {b0.x, b0.y, b0.z, b0.w, b1v.x, b1v.y, b1v.z, b1v.w};
            #pragma unroll
            for (int i = 0; i < 4; ++i)
                #pragma unroll
                for (int j = 0; j < 8; ++j)
                    acc[i][j] = fmaf(ar[i], br[j], acc[i][j]);
        }
        __syncthreads();
    }

    float* yb2 = y2 + ((size_t)b*NC2 + o1)*NN + n1;
    #pragma unroll
    for (int i = 0; i < 4; ++i) {
        float bias = b2[o1 + og + i];
        float4 w0 = make_float4(acc[i][0]+bias, acc[i][1]+bias, acc[i][2]+bias, acc[i][3]+bias);
        float4 w1 = make_float4(acc[i][4]+bias, acc[i][5]+bias, acc[i][6]+bias, acc[i][7]+bias);
        *(float4*)(yb2 + (size_t)(og+i)*NN + ng)     = w0;
        *(float4*)(yb2 + (size_t)(og+i)*NN + ng + 4) = w1;
    }
}

// ---------------------------------------------------------------------------
// Final: out[b][n][o] = relu((y2[b][o][n]-mu2)*rs2), transposed via LDS tile.
// Tile: 64 n x 128 o.
// ---------------------------------------------------------------------------
__global__ __launch_bounds__(256) void k_final(
    const float* __restrict__ y2, const float* __restrict__ mu2,
    const float* __restrict__ rs2, float* __restrict__ out)
{
    __shared__ float L[128*65];
    const int t  = threadIdx.x;
    const int b  = blockIdx.y;
    const int n1 = blockIdx.x * 64;
    const float* yb = y2 + (size_t)b*NC2*NN;
    #pragma unroll
    for (int i = 0; i < 32; ++i) {
        int e = t + i*256;
        int o = e >> 6, nl = e & 63;
        float v = yb[(size_t)o*NN + n1 + nl];
        v = fmaxf(0.f, (v - mu2[b*NC2 + o]) * rs2[b*NC2 + o]);
        L[o*65 + nl] = v;
    }
    __syncthreads();
    float* ob = out + ((size_t)b*NN + n1)*NC2;
    #pragma unroll
    for (int i = 0; i < 32; ++i) {
        int e = t + i*256;
        int o = e & 127, nl = e >> 7;
        ob[(size_t)nl*NC2 + o] = L[o*65 + nl];
    }
}

// ---------------------------------------------------------------------------
extern "C" void kernel_launch(void* const* d_in, const int* in_sizes, int n_in,
                              void* d_out, int out_size, void* d_ws, size_t ws_size,
                              hipStream_t stream) {
    const float* xyz1    = (const float*)d_in[0];
    const float* xyz2    = (const float*)d_in[1];
    const float* points1 = (const float*)d_in[2];
    const float* points2 = (const float*)d_in[3];
    const float* W1      = (const float*)d_in[4];
    const float* b1      = (const float*)d_in[5];
    const float* W2      = (const float*)d_in[6];
    const float* b2      = (const float*)d_in[7];
    float* out = (float*)d_out;

    char* ws = (char*)d_ws;
    float* x   = (float*)(ws);                         // 100,663,296 B
    float* y1  = (float*)(ws + 100663296);             // 67,108,864 B
    float* y2  = (float*)(ws);                         // reuse x region (x dead after gemm1)
    float* mu1 = (float*)(ws + 167772160);             // 2048 f
    float* rs1 = mu1 + 2048;
    float* mu2 = rs1 + 2048;                           // 1024 f
    float* rs2 = mu2 + 1024;

    k_knn_interp<<<dim3(NN/256, NB), 256, 0, stream>>>(xyz1, xyz2, points1, points2, x);
    k_gemm1<<<dim3(NN/128, NC1/64, NB), 256, 0, stream>>>(x, W1, b1, y1);
    k_rowstats<<<NB*NC1, 256, 0, stream>>>(y1, mu1, rs1);
    k_gemm2<<<dim3(NN/128, NC2/64, NB), 256, 0, stream>>>(y1, W2, b2, mu1, rs1, y2);
    k_rowstats<<<NB*NC2, 256, 0, stream>>>(y2, mu2, rs2);
    k_final<<<dim3(NN/64, NB), 256, 0, stream>>>(y2, mu2, rs2, out);
}

// Round 2
// 461.068 us; speedup vs baseline: 1.3322x; 1.3322x over previous
//
#include <hip/hip_runtime.h>
#include <math.h>

#define NB   8
#define NN   8192
#define NS   2048
#define ND1  128
#define ND2  256
#define NCIN 384
#define NC1  256
#define NC2  128

#define EPS_ITP 1e-8f
#define EPS_INORM 1e-5f

// ---------------------------------------------------------------------------
// Kernel 1: 3-NN + inverse-distance interpolation + concat -> x [B][N][384]
// One block = 64 points; 4 thread-slices per point each scan 512 candidates,
// partial top-3 merged via LDS. xyz2[b] staged in LDS as (x,y,z,|q|^2).
// Grid = 128x8 = 1024 blocks; LDS 40448B -> 4 blocks/CU -> 16 waves/CU.
// ---------------------------------------------------------------------------
__global__ __launch_bounds__(256) void k_knn_interp(
    const float* __restrict__ xyz1, const float* __restrict__ xyz2,
    const float* __restrict__ points1, const float* __restrict__ points2,
    float* __restrict__ x)
{
    __shared__ float q[NS * 4];
    __shared__ float sd[4][64][3];
    __shared__ int   sl[4][64][3];
    __shared__ float sw[64][3];
    __shared__ int   si[64][3];
    const int t  = threadIdx.x;
    const int b  = blockIdx.y;
    const int n0 = blockIdx.x * 64;

    const float* xz2 = xyz2 + b * NS * 3;
    for (int e = t; e < NS * 3; e += 256)
        q[(e / 3) * 4 + (e % 3)] = xz2[e];
    __syncthreads();
    for (int s = t; s < NS; s += 256) {
        float qx = q[s*4+0], qy = q[s*4+1], qz = q[s*4+2];
        q[s*4+3] = qx*qx + qy*qy + qz*qz;
    }
    __syncthreads();

    const int p  = t & 63;     // point within block (== lane)
    const int ss = t >> 6;     // candidate slice (== wave id)
    const int n  = n0 + p;
    const float px = xyz1[(b*NN + n)*3 + 0];
    const float py = xyz1[(b*NN + n)*3 + 1];
    const float pz = xyz1[(b*NN + n)*3 + 2];
    const float p2 = px*px + py*py + pz*pz;

    // slice-local top-3 smallest d = |p|^2 + |q|^2 - 2 p.q (same fma order
    // as the verified full-scan version -> identical selection)
    float d0 = 3.4e38f, d1 = 3.4e38f, d2 = 3.4e38f;
    int   i0 = 0, i1 = 0, i2 = 0;
    const int sbeg = ss * (NS/4);
    const int send = sbeg + (NS/4);
    for (int s = sbeg; s < send; ++s) {
        float4 qq = *(const float4*)&q[s*4];
        float dot = px*qq.x + py*qq.y + pz*qq.z;
        float d = p2 + qq.w - 2.0f*dot;
        if (d < d2) {
            if (d < d1) {
                if (d < d0) { d2=d1; i2=i1; d1=d0; i1=i0; d0=d; i0=s; }
                else        { d2=d1; i2=i1; d1=d;  i1=s; }
            } else          { d2=d;  i2=s; }
        }
    }
    sd[ss][p][0] = d0; sd[ss][p][1] = d1; sd[ss][p][2] = d2;
    sl[ss][p][0] = i0; sl[ss][p][1] = i1; sl[ss][p][2] = i2;
    __syncthreads();

    // merge 4 slices' top-3 (12 entries) -> global top-3; wave 0 only.
    // slice-major scan order + strict < keeps first-occurrence tie semantics.
    if (t < 64) {
        float dv[12]; int iv[12];
        #pragma unroll
        for (int m = 0; m < 4; ++m)
            #pragma unroll
            for (int k = 0; k < 3; ++k) {
                dv[m*3+k] = sd[m][t][k];
                iv[m*3+k] = sl[m][t][k];
            }
        float bd[3]; int bi[3];
        #pragma unroll
        for (int r = 0; r < 3; ++r) {
            int best = 0; float bv = dv[0];
            #pragma unroll
            for (int m = 1; m < 12; ++m)
                if (dv[m] < bv) { bv = dv[m]; best = m; }
            bd[r] = bv; bi[r] = iv[best]; dv[best] = 3.4e38f;
        }
        float r0 = 1.0f/(bd[0]+EPS_ITP), r1 = 1.0f/(bd[1]+EPS_ITP), r2 = 1.0f/(bd[2]+EPS_ITP);
        float rsum = r0 + r1 + r2;
        sw[t][0] = r0/rsum; sw[t][1] = r1/rsum; sw[t][2] = r2/rsum;
        si[t][0] = bi[0];   si[t][1] = bi[1];   si[t][2] = bi[2];
    }
    __syncthreads();

    // copy points1 -> x[:, 0:128]  (64 rows x 32 float4, 8 per thread)
    const float* p1 = points1 + (size_t)(b*NN + n0) * ND1;
    float* xb = x + (size_t)(b*NN + n0) * NCIN;
    #pragma unroll
    for (int i = 0; i < 8; ++i) {
        int e   = t + i*256;
        int row = e >> 5;
        int c4  = (e & 31) << 2;
        *(float4*)(xb + (size_t)row*NCIN + c4) = *(const float4*)(p1 + row*ND1 + c4);
    }
    // interpolate -> x[:, 128:384]  (lane = channel, 1KB coalesced gathers)
    const float* p2b = points2 + (size_t)b*NS*ND2;
    for (int j = 0; j < 64; ++j) {
        float w0 = sw[j][0], w1 = sw[j][1], w2 = sw[j][2];
        int   a0 = si[j][0], a1 = si[j][1], a2 = si[j][2];
        float v = w0*p2b[a0*ND2 + t] + w1*p2b[a1*ND2 + t] + w2*p2b[a2*ND2 + t];
        xb[(size_t)j*NCIN + ND1 + t] = v;
    }
}

// ---------------------------------------------------------------------------
// GEMM1: y1[b][o][n] = b1[o] + sum_c W1[o][c] * x[b][n][c]
// block tile 64(o) x 128(n), BK=32, micro-tile 4x8 per thread.
// ---------------------------------------------------------------------------
__global__ __launch_bounds__(256) void k_gemm1(
    const float* __restrict__ x, const float* __restrict__ W1,
    const float* __restrict__ b1, float* __restrict__ y1)
{
    __shared__ float As[32*68];
    __shared__ float Bs[32*132];
    const int t  = threadIdx.x;
    const int n1 = blockIdx.x * 128;
    const int o1 = blockIdx.y * 64;
    const int b  = blockIdx.z;

    const float* xb = x + (size_t)b*NN*NCIN;
    float acc[4][8];
    #pragma unroll
    for (int i = 0; i < 4; ++i)
        #pragma unroll
        for (int j = 0; j < 8; ++j) acc[i][j] = 0.f;

    const int og = (t>>4)<<2;
    const int ng = (t&15)<<3;
    const int ao = t>>2, ak = (t&3)<<3;
    const int bn = t>>1, bk = (t&1)<<4;

    const float* asrc = W1 + (size_t)(o1+ao)*NCIN + ak;
    const float* bsrc = xb + (size_t)(n1+bn)*NCIN + bk;

    for (int k0 = 0; k0 < NCIN; k0 += 32) {
        float4 a0 = *(const float4*)(asrc + k0);
        float4 a1 = *(const float4*)(asrc + k0 + 4);
        float4 v0 = *(const float4*)(bsrc + k0);
        float4 v1 = *(const float4*)(bsrc + k0 + 4);
        float4 v2 = *(const float4*)(bsrc + k0 + 8);
        float4 v3 = *(const float4*)(bsrc + k0 + 12);
        As[(ak+0)*68+ao] = a0.x; As[(ak+1)*68+ao] = a0.y;
        As[(ak+2)*68+ao] = a0.z; As[(ak+3)*68+ao] = a0.w;
        As[(ak+4)*68+ao] = a1.x; As[(ak+5)*68+ao] = a1.y;
        As[(ak+6)*68+ao] = a1.z; As[(ak+7)*68+ao] = a1.w;
        Bs[(bk+ 0)*132+bn] = v0.x; Bs[(bk+ 1)*132+bn] = v0.y;
        Bs[(bk+ 2)*132+bn] = v0.z; Bs[(bk+ 3)*132+bn] = v0.w;
        Bs[(bk+ 4)*132+bn] = v1.x; Bs[(bk+ 5)*132+bn] = v1.y;
        Bs[(bk+ 6)*132+bn] = v1.z; Bs[(bk+ 7)*132+bn] = v1.w;
        Bs[(bk+ 8)*132+bn] = v2.x; Bs[(bk+ 9)*132+bn] = v2.y;
        Bs[(bk+10)*132+bn] = v2.z; Bs[(bk+11)*132+bn] = v2.w;
        Bs[(bk+12)*132+bn] = v3.x; Bs[(bk+13)*132+bn] = v3.y;
        Bs[(bk+14)*132+bn] = v3.z; Bs[(bk+15)*132+bn] = v3.w;
        __syncthreads();
        #pragma unroll 8
        for (int k = 0; k < 32; ++k) {
            float4 aa = *(const float4*)&As[k*68 + og];
            float4 b0 = *(const float4*)&Bs[k*132 + ng];
            float4 b1v = *(const float4*)&Bs[k*132 + ng + 4];
            float ar[4] = {aa.x, aa.y, aa.z, aa.w};
            float br[8] = {b0.x, b0.y, b0.z, b0.w, b1v.x, b1v.y, b1v.z, b1v.w};
            #pragma unroll
            for (int i = 0; i < 4; ++i)
                #pragma unroll
                for (int j = 0; j < 8; ++j)
                    acc[i][j] = fmaf(ar[i], br[j], acc[i][j]);
        }
        __syncthreads();
    }

    float* yb = y1 + ((size_t)b*NC1 + o1)*NN + n1;
    #pragma unroll
    for (int i = 0; i < 4; ++i) {
        float bias = b1[o1 + og + i];
        float4 w0 = make_float4(acc[i][0]+bias, acc[i][1]+bias, acc[i][2]+bias, acc[i][3]+bias);
        float4 w1 = make_float4(acc[i][4]+bias, acc[i][5]+bias, acc[i][6]+bias, acc[i][7]+bias);
        *(float4*)(yb + (size_t)(og+i)*NN + ng)     = w0;
        *(float4*)(yb + (size_t)(og+i)*NN + ng + 4) = w1;
    }
}

// ---------------------------------------------------------------------------
// Row stats: mean + 1/sqrt(var+eps) per row of length NN (biased var).
// ---------------------------------------------------------------------------
__global__ __launch_bounds__(256) void k_rowstats(
    const float* __restrict__ y, float* __restrict__ mu, float* __restrict__ rs)
{
    const int row = blockIdx.x;
    const float4* p = (const float4*)(y + (size_t)row * NN);
    float s = 0.f, s2 = 0.f;
    for (int i = threadIdx.x; i < NN/4; i += 256) {
        float4 v = p[i];
        s  += v.x + v.y + v.z + v.w;
        s2 += v.x*v.x + v.y*v.y + v.z*v.z + v.w*v.w;
    }
    #pragma unroll
    for (int off = 32; off > 0; off >>= 1) {
        s  += __shfl_down(s,  off, 64);
        s2 += __shfl_down(s2, off, 64);
    }
    __shared__ float ls[4], ls2[4];
    const int wid  = threadIdx.x >> 6;
    const int lane = threadIdx.x & 63;
    if (lane == 0) { ls[wid] = s; ls2[wid] = s2; }
    __syncthreads();
    if (threadIdx.x == 0) {
        float S  = ls[0]+ls[1]+ls[2]+ls[3];
        float S2 = ls2[0]+ls2[1]+ls2[2]+ls2[3];
        float m  = S / (float)NN;
        float var = S2 / (float)NN - m*m;
        mu[row] = m;
        rs[row] = 1.0f / sqrtf(var + EPS_INORM);
    }
}

// ---------------------------------------------------------------------------
// GEMM2: y2[b][o][n] = b2[o] + sum_c W2[o][c] * relu((y1[b][c][n]-mu1)*rs1)
// ---------------------------------------------------------------------------
__global__ __launch_bounds__(256) void k_gemm2(
    const float* __restrict__ y1, const float* __restrict__ W2,
    const float* __restrict__ b2, const float* __restrict__ mu1,
    const float* __restrict__ rs1, float* __restrict__ y2)
{
    __shared__ float As[32*68];
    __shared__ float Bs[32*132];
    const int t  = threadIdx.x;
    const int n1 = blockIdx.x * 128;
    const int o1 = blockIdx.y * 64;
    const int b  = blockIdx.z;

    const float* yb1 = y1 + (size_t)b*NC1*NN;
    float acc[4][8];
    #pragma unroll
    for (int i = 0; i < 4; ++i)
        #pragma unroll
        for (int j = 0; j < 8; ++j) acc[i][j] = 0.f;

    const int og = (t>>4)<<2;
    const int ng = (t&15)<<3;
    const int ao = t>>2, ak = (t&3)<<3;
    const int bkr = t>>3;
    const int bnn = (t&7)<<4;

    const float* asrc = W2 + (size_t)(o1+ao)*NC1 + ak;

    for (int k0 = 0; k0 < NC1; k0 += 32) {
        float4 a0 = *(const float4*)(asrc + k0);
        float4 a1 = *(const float4*)(asrc + k0 + 4);
        const float* bsrc = yb1 + (size_t)(k0 + bkr)*NN + n1 + bnn;
        float m = mu1[b*NC1 + k0 + bkr];
        float r = rs1[b*NC1 + k0 + bkr];
        float4 v0 = *(const float4*)(bsrc);
        float4 v1 = *(const float4*)(bsrc + 4);
        float4 v2 = *(const float4*)(bsrc + 8);
        float4 v3 = *(const float4*)(bsrc + 12);
        v0.x = fmaxf(0.f,(v0.x-m)*r); v0.y = fmaxf(0.f,(v0.y-m)*r);
        v0.z = fmaxf(0.f,(v0.z-m)*r); v0.w = fmaxf(0.f,(v0.w-m)*r);
        v1.x = fmaxf(0.f,(v1.x-m)*r); v1.y = fmaxf(0.f,(v1.y-m)*r);
        v1.z = fmaxf(0.f,(v1.z-m)*r); v1.w = fmaxf(0.f,(v1.w-m)*r);
        v2.x = fmaxf(0.f,(v2.x-m)*r); v2.y = fmaxf(0.f,(v2.y-m)*r);
        v2.z = fmaxf(0.f,(v2.z-m)*r); v2.w = fmaxf(0.f,(v2.w-m)*r);
        v3.x = fmaxf(0.f,(v3.x-m)*r); v3.y = fmaxf(0.f,(v3.y-m)*r);
        v3.z = fmaxf(0.f,(v3.z-m)*r); v3.w = fmaxf(0.f,(v3.w-m)*r);
        As[(ak+0)*68+ao] = a0.x; As[(ak+1)*68+ao] = a0.y;
        As[(ak+2)*68+ao] = a0.z; As[(ak+3)*68+ao] = a0.w;
        As[(ak+4)*68+ao] = a1.x; As[(ak+5)*68+ao] = a1.y;
        As[(ak+6)*68+ao] = a1.z; As[(ak+7)*68+ao] = a1.w;
        float* bd = &Bs[bkr*132 + bnn];
        bd[0]=v0.x; bd[1]=v0.y; bd[2]=v0.z; bd[3]=v0.w;
        bd[4]=v1.x; bd[5]=v1.y; bd[6]=v1.z; bd[7]=v1.w;
        bd[8]=v2.x; bd[9]=v2.y; bd[10]=v2.z; bd[11]=v2.w;
        bd[12]=v3.x; bd[13]=v3.y; bd[14]=v3.z; bd[15]=v3.w;
        __syncthreads();
        #pragma unroll 8
        for (int k = 0; k < 32; ++k) {
            float4 aa = *(const float4*)&As[k*68 + og];
            float4 b0 = *(const float4*)&Bs[k*132 + ng];
            float4 b1v = *(const float4*)&Bs[k*132 + ng + 4];
            float ar[4] = {aa.x, aa.y, aa.z, aa.w};
            float br[8] = {b0.x, b0.y, b0.z, b0.w, b1v.x, b1v.y, b1v.z, b1v.w};
            #pragma unroll
            for (int i = 0; i < 4; ++i)
                #pragma unroll
                for (int j = 0; j < 8; ++j)
                    acc[i][j] = fmaf(ar[i], br[j], acc[i][j]);
        }
        __syncthreads();
    }

    float* yb2 = y2 + ((size_t)b*NC2 + o1)*NN + n1;
    #pragma unroll
    for (int i = 0; i < 4; ++i) {
        float bias = b2[o1 + og + i];
        float4 w0 = make_float4(acc[i][0]+bias, acc[i][1]+bias, acc[i][2]+bias, acc[i][3]+bias);
        float4 w1 = make_float4(acc[i][4]+bias, acc[i][5]+bias, acc[i][6]+bias, acc[i][7]+bias);
        *(float4*)(yb2 + (size_t)(og+i)*NN + ng)     = w0;
        *(float4*)(yb2 + (size_t)(og+i)*NN + ng + 4) = w1;
    }
}

// ---------------------------------------------------------------------------
// Final: out[b][n][o] = relu((y2[b][o][n]-mu2)*rs2), transposed via LDS tile.
// ---------------------------------------------------------------------------
__global__ __launch_bounds__(256) void k_final(
    const float* __restrict__ y2, const float* __restrict__ mu2,
    const float* __restrict__ rs2, float* __restrict__ out)
{
    __shared__ float L[128*65];
    const int t  = threadIdx.x;
    const int b  = blockIdx.y;
    const int n1 = blockIdx.x * 64;
    const float* yb = y2 + (size_t)b*NC2*NN;
    #pragma unroll
    for (int i = 0; i < 32; ++i) {
        int e = t + i*256;
        int o = e >> 6, nl = e & 63;
        float v = yb[(size_t)o*NN + n1 + nl];
        v = fmaxf(0.f, (v - mu2[b*NC2 + o]) * rs2[b*NC2 + o]);
        L[o*65 + nl] = v;
    }
    __syncthreads();
    float* ob = out + ((size_t)b*NN + n1)*NC2;
    #pragma unroll
    for (int i = 0; i < 32; ++i) {
        int e = t + i*256;
        int o = e & 127, nl = e >> 7;
        ob[(size_t)nl*NC2 + o] = L[o*65 + nl];
    }
}

// ---------------------------------------------------------------------------
extern "C" void kernel_launch(void* const* d_in, const int* in_sizes, int n_in,
                              void* d_out, int out_size, void* d_ws, size_t ws_size,
                              hipStream_t stream) {
    const float* xyz1    = (const float*)d_in[0];
    const float* xyz2    = (const float*)d_in[1];
    const float* points1 = (const float*)d_in[2];
    const float* points2 = (const float*)d_in[3];
    const float* W1      = (const float*)d_in[4];
    const float* b1      = (const float*)d_in[5];
    const float* W2      = (const float*)d_in[6];
    const float* b2      = (const float*)d_in[7];
    float* out = (float*)d_out;

    char* ws = (char*)d_ws;
    float* x   = (float*)(ws);                         // 100,663,296 B
    float* y1  = (float*)(ws + 100663296);             // 67,108,864 B
    float* y2  = (float*)(ws);                         // reuse x region
    float* mu1 = (float*)(ws + 167772160);
    float* rs1 = mu1 + 2048;
    float* mu2 = rs1 + 2048;
    float* rs2 = mu2 + 1024;

    k_knn_interp<<<dim3(NN/64, NB), 256, 0, stream>>>(xyz1, xyz2, points1, points2, x);
    k_gemm1<<<dim3(NN/128, NC1/64, NB), 256, 0, stream>>>(x, W1, b1, y1);
    k_rowstats<<<NB*NC1, 256, 0, stream>>>(y1, mu1, rs1);
    k_gemm2<<<dim3(NN/128, NC2/64, NB), 256, 0, stream>>>(y1, W2, b2, mu1, rs1, y2);
    k_rowstats<<<NB*NC2, 256, 0, stream>>>(y2, mu2, rs2);
    k_final<<<dim3(NN/64, NB), 256, 0, stream>>>(y2, mu2, rs2, out);
}

// Round 3
// 339.884 us; speedup vs baseline: 1.8072x; 1.3565x over previous
//
#include <hip/hip_runtime.h>
#include <math.h>

#define NB   8
#define NN   8192
#define NS   2048
#define ND1  128
#define ND2  256
#define NCIN 384
#define NC1  256
#define NC2  128

#define EPS_ITP 1e-8f
#define EPS_INORM 1e-5f

typedef float f32x4 __attribute__((ext_vector_type(4)));
typedef short s16x8 __attribute__((ext_vector_type(8)));
typedef short s16x4 __attribute__((ext_vector_type(4)));
typedef short s16x2 __attribute__((ext_vector_type(2)));

// RNE float->bf16 (finite inputs)
static __device__ __forceinline__ short f2bf(float f) {
    unsigned u = __float_as_uint(f);
    unsigned r = (u + 0x7FFFu + ((u >> 16) & 1u)) >> 16;
    return (short)r;
}

// ---------------------------------------------------------------------------
// Kernel 1: 3-NN + inverse-distance interp + concat -> x bf16 [B][N][384]
// 64 points/block, 4 slices/point scan 512 candidates each, LDS merge.
// ---------------------------------------------------------------------------
__global__ __launch_bounds__(256) void k_knn_interp(
    const float* __restrict__ xyz1, const float* __restrict__ xyz2,
    const float* __restrict__ points1, const float* __restrict__ points2,
    unsigned short* __restrict__ xb)
{
    __shared__ float q[NS * 4];
    __shared__ float sd[4][64][3];
    __shared__ int   sl[4][64][3];
    __shared__ float sw[64][3];
    __shared__ int   si[64][3];
    const int t  = threadIdx.x;
    const int b  = blockIdx.y;
    const int n0 = blockIdx.x * 64;

    const float* xz2 = xyz2 + b * NS * 3;
    for (int e = t; e < NS * 3; e += 256)
        q[(e / 3) * 4 + (e % 3)] = xz2[e];
    __syncthreads();
    for (int s = t; s < NS; s += 256) {
        float qx = q[s*4+0], qy = q[s*4+1], qz = q[s*4+2];
        q[s*4+3] = qx*qx + qy*qy + qz*qz;
    }
    __syncthreads();

    const int p  = t & 63;
    const int ss = t >> 6;
    const int n  = n0 + p;
    const float px = xyz1[(b*NN + n)*3 + 0];
    const float py = xyz1[(b*NN + n)*3 + 1];
    const float pz = xyz1[(b*NN + n)*3 + 2];
    const float p2 = px*px + py*py + pz*pz;

    float d0 = 3.4e38f, d1 = 3.4e38f, d2 = 3.4e38f;
    int   i0 = 0, i1 = 0, i2 = 0;
    const int sbeg = ss * (NS/4);
    const int send = sbeg + (NS/4);
    for (int s = sbeg; s < send; ++s) {
        float4 qq = *(const float4*)&q[s*4];
        float dot = px*qq.x + py*qq.y + pz*qq.z;
        float d = p2 + qq.w - 2.0f*dot;
        if (d < d2) {
            if (d < d1) {
                if (d < d0) { d2=d1; i2=i1; d1=d0; i1=i0; d0=d; i0=s; }
                else        { d2=d1; i2=i1; d1=d;  i1=s; }
            } else          { d2=d;  i2=s; }
        }
    }
    sd[ss][p][0] = d0; sd[ss][p][1] = d1; sd[ss][p][2] = d2;
    sl[ss][p][0] = i0; sl[ss][p][1] = i1; sl[ss][p][2] = i2;
    __syncthreads();

    if (t < 64) {
        float dv[12]; int iv[12];
        #pragma unroll
        for (int m = 0; m < 4; ++m)
            #pragma unroll
            for (int k = 0; k < 3; ++k) {
                dv[m*3+k] = sd[m][t][k];
                iv[m*3+k] = sl[m][t][k];
            }
        float bd[3]; int bi[3];
        #pragma unroll
        for (int r = 0; r < 3; ++r) {
            int best = 0; float bv = dv[0];
            #pragma unroll
            for (int m = 1; m < 12; ++m)
                if (dv[m] < bv) { bv = dv[m]; best = m; }
            bd[r] = bv; bi[r] = iv[best]; dv[best] = 3.4e38f;
        }
        float r0 = 1.0f/(bd[0]+EPS_ITP), r1 = 1.0f/(bd[1]+EPS_ITP), r2 = 1.0f/(bd[2]+EPS_ITP);
        float rsum = r0 + r1 + r2;
        sw[t][0] = r0/rsum; sw[t][1] = r1/rsum; sw[t][2] = r2/rsum;
        si[t][0] = bi[0];   si[t][1] = bi[1];   si[t][2] = bi[2];
    }
    __syncthreads();

    // points1 -> x[:, 0:128] as bf16
    const float* p1 = points1 + (size_t)(b*NN + n0) * ND1;
    unsigned short* xrow = xb + (size_t)(b*NN + n0) * NCIN;
    #pragma unroll
    for (int i = 0; i < 8; ++i) {
        int e   = t + i*256;
        int row = e >> 5;
        int c4  = (e & 31) << 2;
        float4 v = *(const float4*)(p1 + (size_t)row*ND1 + c4);
        s16x4 o;
        o[0] = f2bf(v.x); o[1] = f2bf(v.y); o[2] = f2bf(v.z); o[3] = f2bf(v.w);
        *(s16x4*)(xrow + (size_t)row*NCIN + c4) = o;
    }
    // interp -> x[:, 128:384] as bf16; 2 rows per iter, 2 channels/thread
    const float* p2b = points2 + (size_t)b*NS*ND2;
    const int half = t >> 7;
    const int c2   = (t & 127) * 2;
    for (int j2 = 0; j2 < 32; ++j2) {
        int j = j2*2 + half;
        float w0 = sw[j][0], w1 = sw[j][1], w2 = sw[j][2];
        int   a0 = si[j][0], a1 = si[j][1], a2 = si[j][2];
        float2 v0 = *(const float2*)(p2b + (size_t)a0*ND2 + c2);
        float2 v1 = *(const float2*)(p2b + (size_t)a1*ND2 + c2);
        float2 v2 = *(const float2*)(p2b + (size_t)a2*ND2 + c2);
        float ox = w0*v0.x + w1*v1.x + w2*v2.x;
        float oy = w0*v0.y + w1*v1.y + w2*v2.y;
        s16x2 o; o[0] = f2bf(ox); o[1] = f2bf(oy);
        *(s16x2*)(xrow + (size_t)j*NCIN + ND1 + c2) = o;
    }
}

// ---------------------------------------------------------------------------
// Weight cast: W1 (256x384) + W2 (128x256) f32 -> bf16, contiguous in Wb.
// ---------------------------------------------------------------------------
__global__ __launch_bounds__(256) void k_castw(
    const float* __restrict__ W1, const float* __restrict__ W2,
    unsigned short* __restrict__ Wb)
{
    int i = blockIdx.x * 256 + threadIdx.x;
    if (i < NC1*NCIN)              Wb[i] = (unsigned short)f2bf(W1[i]);
    else if (i < NC1*NCIN + NC2*NC1) Wb[i] = (unsigned short)f2bf(W2[i - NC1*NCIN]);
}

__global__ __launch_bounds__(256) void k_zero(float* __restrict__ p) {
    p[blockIdx.x * 256 + threadIdx.x] = 0.f;
}

// ---------------------------------------------------------------------------
// GEMM1 (MFMA): y1[b][n][o] = b1[o] + sum_c W1[o][c]*x[b][n][c]
// Block: 64(o) x 128(n); wave tile 64(o) x 32(n); direct-global fragments.
// ---------------------------------------------------------------------------
__global__ __launch_bounds__(256) void k_gemm1(
    const unsigned short* __restrict__ Xb, const unsigned short* __restrict__ W1b,
    const float* __restrict__ b1, float* __restrict__ y1)
{
    const int t   = threadIdx.x;
    const int w   = t >> 6;
    const int l   = t & 63;
    const int l16 = l & 15, lk = l >> 4;
    const int n1  = blockIdx.x * 128 + w * 32;
    const int o1  = blockIdx.y * 64;
    const int b   = blockIdx.z;

    const unsigned short* xrow = Xb + (size_t)b * NN * NCIN;
    f32x4 acc[4][2] = {};

    const unsigned short* ap[4];
    const unsigned short* bp[2];
    #pragma unroll
    for (int m = 0; m < 4; ++m)
        ap[m] = W1b + (size_t)(o1 + m*16 + l16) * NCIN + lk*8;
    #pragma unroll
    for (int nn = 0; nn < 2; ++nn)
        bp[nn] = xrow + (size_t)(n1 + nn*16 + l16) * NCIN + lk*8;

    #pragma unroll 2
    for (int k0 = 0; k0 < NCIN; k0 += 32) {
        s16x8 af[4], bf[2];
        #pragma unroll
        for (int m = 0; m < 4; ++m) af[m] = *(const s16x8*)(ap[m] + k0);
        #pragma unroll
        for (int nn = 0; nn < 2; ++nn) bf[nn] = *(const s16x8*)(bp[nn] + k0);
        #pragma unroll
        for (int m = 0; m < 4; ++m)
            #pragma unroll
            for (int nn = 0; nn < 2; ++nn)
                acc[m][nn] = __builtin_amdgcn_mfma_f32_16x16x32_bf16(
                    af[m], bf[nn], acc[m][nn], 0, 0, 0);
    }

    float* yb = y1 + (size_t)b * NN * NC1;
    #pragma unroll
    for (int m = 0; m < 4; ++m) {
        f32x4 bias = *(const f32x4*)(b1 + o1 + m*16 + lk*4);
        #pragma unroll
        for (int nn = 0; nn < 2; ++nn) {
            int nidx = n1 + nn*16 + l16;
            f32x4 v = acc[m][nn] + bias;
            *(f32x4*)(yb + (size_t)nidx*NC1 + o1 + m*16 + lk*4) = v;
        }
    }
}

// ---------------------------------------------------------------------------
// Stats over n for y [b][n][C] (C=256): per-block partial sums + atomics.
// ---------------------------------------------------------------------------
__global__ __launch_bounds__(256) void k_stats1(
    const float* __restrict__ y, float* __restrict__ S, float* __restrict__ S2)
{
    const int t = threadIdx.x;
    const int b = blockIdx.y;
    const float* p = y + ((size_t)b*NN + (size_t)blockIdx.x*256) * NC1 + t;
    float s = 0.f, q = 0.f;
    for (int r = 0; r < 256; ++r) {
        float v = p[(size_t)r * NC1];
        s += v; q += v*v;
    }
    atomicAdd(&S [b*NC1 + t], s);
    atomicAdd(&S2[b*NC1 + t], q);
}

__global__ __launch_bounds__(256) void k_stats2(
    const float* __restrict__ y, float* __restrict__ S, float* __restrict__ S2)
{
    const int t = threadIdx.x;
    const int b = blockIdx.y;
    const int c = t & 127;
    const int h = t >> 7;
    const float* p = y + ((size_t)b*NN + (size_t)blockIdx.x*512 + h) * NC2 + c;
    float s = 0.f, q = 0.f;
    for (int r = 0; r < 256; ++r) {
        float v = p[(size_t)(2*r) * NC2];
        s += v; q += v*v;
    }
    atomicAdd(&S [b*NC2 + c], s);
    atomicAdd(&S2[b*NC2 + c], q);
}

__global__ __launch_bounds__(256) void k_finstats(
    const float* __restrict__ S, const float* __restrict__ S2,
    float* __restrict__ mu, float* __restrict__ rs, int nent)
{
    int i = blockIdx.x * 256 + threadIdx.x;
    if (i < nent) {
        float m = S[i] * (1.0f/(float)NN);
        float var = S2[i] * (1.0f/(float)NN) - m*m;
        mu[i] = m;
        rs[i] = 1.0f / sqrtf(var + EPS_INORM);
    }
}

// ---------------------------------------------------------------------------
// GEMM2 (MFMA): y2[b][n][o] = b2[o] + sum_c W2[o][c]*relu((y1[b][n][c]-mu)*rs)
// B-fragment built on the fly from f32 y1 (norm+relu+cvt).
// ---------------------------------------------------------------------------
__global__ __launch_bounds__(256) void k_gemm2(
    const float* __restrict__ y1, const unsigned short* __restrict__ W2b,
    const float* __restrict__ b2, const float* __restrict__ mu1,
    const float* __restrict__ rs1, float* __restrict__ y2)
{
    const int t   = threadIdx.x;
    const int w   = t >> 6;
    const int l   = t & 63;
    const int l16 = l & 15, lk = l >> 4;
    const int n1  = blockIdx.x * 128 + w * 32;
    const int o1  = blockIdx.y * 64;
    const int b   = blockIdx.z;

    const float* yrow = y1 + (size_t)b * NN * NC1;
    const float* mu = mu1 + b * NC1;
    const float* rs = rs1 + b * NC1;
    f32x4 acc[4][2] = {};

    const unsigned short* ap[4];
    const float* bp[2];
    #pragma unroll
    for (int m = 0; m < 4; ++m)
        ap[m] = W2b + (size_t)(o1 + m*16 + l16) * NC1 + lk*8;
    #pragma unroll
    for (int nn = 0; nn < 2; ++nn)
        bp[nn] = yrow + (size_t)(n1 + nn*16 + l16) * NC1 + lk*8;

    #pragma unroll 2
    for (int k0 = 0; k0 < NC1; k0 += 32) {
        f32x4 m0 = *(const f32x4*)(mu + k0 + lk*8);
        f32x4 m1 = *(const f32x4*)(mu + k0 + lk*8 + 4);
        f32x4 s0 = *(const f32x4*)(rs + k0 + lk*8);
        f32x4 s1 = *(const f32x4*)(rs + k0 + lk*8 + 4);
        s16x8 af[4], bf[2];
        #pragma unroll
        for (int m = 0; m < 4; ++m) af[m] = *(const s16x8*)(ap[m] + k0);
        #pragma unroll
        for (int nn = 0; nn < 2; ++nn) {
            f32x4 r0 = *(const f32x4*)(bp[nn] + k0);
            f32x4 r1 = *(const f32x4*)(bp[nn] + k0 + 4);
            s16x8 v;
            #pragma unroll
            for (int j = 0; j < 4; ++j)
                v[j] = f2bf(fmaxf(0.f, (r0[j]-m0[j])*s0[j]));
            #pragma unroll
            for (int j = 0; j < 4; ++j)
                v[4+j] = f2bf(fmaxf(0.f, (r1[j]-m1[j])*s1[j]));
            bf[nn] = v;
        }
        #pragma unroll
        for (int m = 0; m < 4; ++m)
            #pragma unroll
            for (int nn = 0; nn < 2; ++nn)
                acc[m][nn] = __builtin_amdgcn_mfma_f32_16x16x32_bf16(
                    af[m], bf[nn], acc[m][nn], 0, 0, 0);
    }

    float* yb = y2 + (size_t)b * NN * NC2;
    #pragma unroll
    for (int m = 0; m < 4; ++m) {
        f32x4 bias = *(const f32x4*)(b2 + o1 + m*16 + lk*4);
        #pragma unroll
        for (int nn = 0; nn < 2; ++nn) {
            int nidx = n1 + nn*16 + l16;
            f32x4 v = acc[m][nn] + bias;
            *(f32x4*)(yb + (size_t)nidx*NC2 + o1 + m*16 + lk*4) = v;
        }
    }
}

// ---------------------------------------------------------------------------
// Final: out[b][n][o] = relu((y2[b][n][o]-mu2[o])*rs2[o])  (pure elementwise)
// ---------------------------------------------------------------------------
__global__ __launch_bounds__(256) void k_final(
    const float* __restrict__ y2, const float* __restrict__ mu2,
    const float* __restrict__ rs2, float* __restrict__ out)
{
    const int total4 = NB * NN * NC2 / 4;
    const int perb4  = NN * NC2 / 4;
    for (int i = blockIdx.x * 256 + threadIdx.x; i < total4; i += gridDim.x * 256) {
        int b  = i / perb4;
        int c4 = (i & 31) * 4;
        f32x4 v = ((const f32x4*)y2)[i];
        f32x4 m = *(const f32x4*)(mu2 + b*NC2 + c4);
        f32x4 r = *(const f32x4*)(rs2 + b*NC2 + c4);
        f32x4 o;
        #pragma unroll
        for (int j = 0; j < 4; ++j) o[j] = fmaxf(0.f, (v[j]-m[j])*r[j]);
        ((f32x4*)out)[i] = o;
    }
}

// ---------------------------------------------------------------------------
extern "C" void kernel_launch(void* const* d_in, const int* in_sizes, int n_in,
                              void* d_out, int out_size, void* d_ws, size_t ws_size,
                              hipStream_t stream) {
    const float* xyz1    = (const float*)d_in[0];
    const float* xyz2    = (const float*)d_in[1];
    const float* points1 = (const float*)d_in[2];
    const float* points2 = (const float*)d_in[3];
    const float* W1      = (const float*)d_in[4];
    const float* b1      = (const float*)d_in[5];
    const float* W2      = (const float*)d_in[6];
    const float* b2      = (const float*)d_in[7];
    float* out = (float*)d_out;

    char* ws = (char*)d_ws;
    unsigned short* xb = (unsigned short*)(ws);            // 50,331,648 B
    float* y1 = (float*)(ws + 50331648);                   // 67,108,864 B
    float* y2 = (float*)(ws + 117440512);                  // 33,554,432 B
    unsigned short* Wb = (unsigned short*)(ws + 150994944);// 262,144 B
    float* accb = (float*)(ws + 151257088);                // 6144 f (zeroed)
    float* S1a = accb;            // 2048
    float* S2a = accb + 2048;     // 2048
    float* T1a = accb + 4096;     // 1024
    float* T2a = accb + 5120;     // 1024
    float* prm = (float*)(ws + 151281664);                 // 6144 f
    float* mu1 = prm;             // 2048
    float* rs1 = prm + 2048;      // 2048
    float* mu2 = prm + 4096;      // 1024
    float* rs2 = prm + 5120;      // 1024
    unsigned short* W2b = Wb + NC1*NCIN;

    k_zero<<<24, 256, 0, stream>>>(accb);
    k_castw<<<512, 256, 0, stream>>>(W1, W2, Wb);
    k_knn_interp<<<dim3(NN/64, NB), 256, 0, stream>>>(xyz1, xyz2, points1, points2, xb);
    k_gemm1<<<dim3(NN/128, NC1/64, NB), 256, 0, stream>>>(xb, Wb, b1, y1);
    k_stats1<<<dim3(NN/256, NB), 256, 0, stream>>>(y1, S1a, S2a);
    k_finstats<<<8, 256, 0, stream>>>(S1a, S2a, mu1, rs1, NB*NC1);
    k_gemm2<<<dim3(NN/128, NC2/64, NB), 256, 0, stream>>>(y1, W2b, b2, mu1, rs1, y2);
    k_stats2<<<dim3(NN/512, NB), 256, 0, stream>>>(y2, T1a, T2a);
    k_finstats<<<4, 256, 0, stream>>>(T1a, T2a, mu2, rs2, NB*NC2);
    k_final<<<2048, 256, 0, stream>>>(y2, mu2, rs2, out);
}

// Round 4
// 301.188 us; speedup vs baseline: 2.0393x; 1.1285x over previous
//
#include <hip/hip_runtime.h>
#include <math.h>

#define NB   8
#define NN   8192
#define NS   2048
#define ND1  128
#define ND2  256
#define NCIN 384
#define NC1  256
#define NC2  128

#define EPS_ITP 1e-8f
#define EPS_INORM 1e-5f

typedef float f32x4 __attribute__((ext_vector_type(4)));
typedef short s16x8 __attribute__((ext_vector_type(8)));
typedef short s16x4 __attribute__((ext_vector_type(4)));
typedef short s16x2 __attribute__((ext_vector_type(2)));

// RNE float->bf16 (finite inputs)
static __device__ __forceinline__ short f2bf(float f) {
    unsigned u = __float_as_uint(f);
    unsigned r = (u + 0x7FFFu + ((u >> 16) & 1u)) >> 16;
    return (short)r;
}
static __device__ __forceinline__ float bflo(unsigned u) { return __uint_as_float(u << 16); }
static __device__ __forceinline__ float bfhi(unsigned u) { return __uint_as_float(u & 0xFFFF0000u); }
// pack 2 f32 -> 2 bf16 in one u32 (lo=a, hi=b)
static __device__ __forceinline__ unsigned pkbf(float a, float b) {
    unsigned r;
    asm("v_cvt_pk_bf16_f32 %0, %1, %2" : "=v"(r) : "v"(a), "v"(b));
    return r;
}

// ---------------------------------------------------------------------------
// Kernel 1: 3-NN + inverse-distance interp + concat -> x bf16 [B][N][384]
// (unchanged from round 3 — passing; optimization deferred)
// ---------------------------------------------------------------------------
__global__ __launch_bounds__(256) void k_knn_interp(
    const float* __restrict__ xyz1, const float* __restrict__ xyz2,
    const float* __restrict__ points1, const float* __restrict__ points2,
    unsigned short* __restrict__ xb)
{
    __shared__ float q[NS * 4];
    __shared__ float sd[4][64][3];
    __shared__ int   sl[4][64][3];
    __shared__ float sw[64][3];
    __shared__ int   si[64][3];
    const int t  = threadIdx.x;
    const int b  = blockIdx.y;
    const int n0 = blockIdx.x * 64;

    const float* xz2 = xyz2 + b * NS * 3;
    for (int e = t; e < NS * 3; e += 256)
        q[(e / 3) * 4 + (e % 3)] = xz2[e];
    __syncthreads();
    for (int s = t; s < NS; s += 256) {
        float qx = q[s*4+0], qy = q[s*4+1], qz = q[s*4+2];
        q[s*4+3] = qx*qx + qy*qy + qz*qz;
    }
    __syncthreads();

    const int p  = t & 63;
    const int ss = t >> 6;
    const int n  = n0 + p;
    const float px = xyz1[(b*NN + n)*3 + 0];
    const float py = xyz1[(b*NN + n)*3 + 1];
    const float pz = xyz1[(b*NN + n)*3 + 2];
    const float p2 = px*px + py*py + pz*pz;

    float d0 = 3.4e38f, d1 = 3.4e38f, d2 = 3.4e38f;
    int   i0 = 0, i1 = 0, i2 = 0;
    const int sbeg = ss * (NS/4);
    const int send = sbeg + (NS/4);
    for (int s = sbeg; s < send; ++s) {
        float4 qq = *(const float4*)&q[s*4];
        float dot = px*qq.x + py*qq.y + pz*qq.z;
        float d = p2 + qq.w - 2.0f*dot;
        if (d < d2) {
            if (d < d1) {
                if (d < d0) { d2=d1; i2=i1; d1=d0; i1=i0; d0=d; i0=s; }
                else        { d2=d1; i2=i1; d1=d;  i1=s; }
            } else          { d2=d;  i2=s; }
        }
    }
    sd[ss][p][0] = d0; sd[ss][p][1] = d1; sd[ss][p][2] = d2;
    sl[ss][p][0] = i0; sl[ss][p][1] = i1; sl[ss][p][2] = i2;
    __syncthreads();

    if (t < 64) {
        float dv[12]; int iv[12];
        #pragma unroll
        for (int m = 0; m < 4; ++m)
            #pragma unroll
            for (int k = 0; k < 3; ++k) {
                dv[m*3+k] = sd[m][t][k];
                iv[m*3+k] = sl[m][t][k];
            }
        float bd[3]; int bi[3];
        #pragma unroll
        for (int r = 0; r < 3; ++r) {
            int best = 0; float bv = dv[0];
            #pragma unroll
            for (int m = 1; m < 12; ++m)
                if (dv[m] < bv) { bv = dv[m]; best = m; }
            bd[r] = bv; bi[r] = iv[best]; dv[best] = 3.4e38f;
        }
        float r0 = 1.0f/(bd[0]+EPS_ITP), r1 = 1.0f/(bd[1]+EPS_ITP), r2 = 1.0f/(bd[2]+EPS_ITP);
        float rsum = r0 + r1 + r2;
        sw[t][0] = r0/rsum; sw[t][1] = r1/rsum; sw[t][2] = r2/rsum;
        si[t][0] = bi[0];   si[t][1] = bi[1];   si[t][2] = bi[2];
    }
    __syncthreads();

    const float* p1 = points1 + (size_t)(b*NN + n0) * ND1;
    unsigned short* xrow = xb + (size_t)(b*NN + n0) * NCIN;
    #pragma unroll
    for (int i = 0; i < 8; ++i) {
        int e   = t + i*256;
        int row = e >> 5;
        int c4  = (e & 31) << 2;
        float4 v = *(const float4*)(p1 + (size_t)row*ND1 + c4);
        s16x4 o;
        o[0] = f2bf(v.x); o[1] = f2bf(v.y); o[2] = f2bf(v.z); o[3] = f2bf(v.w);
        *(s16x4*)(xrow + (size_t)row*NCIN + c4) = o;
    }
    const float* p2b = points2 + (size_t)b*NS*ND2;
    const int half = t >> 7;
    const int c2   = (t & 127) * 2;
    for (int j2 = 0; j2 < 32; ++j2) {
        int j = j2*2 + half;
        float w0 = sw[j][0], w1 = sw[j][1], w2 = sw[j][2];
        int   a0 = si[j][0], a1 = si[j][1], a2 = si[j][2];
        float2 v0 = *(const float2*)(p2b + (size_t)a0*ND2 + c2);
        float2 v1 = *(const float2*)(p2b + (size_t)a1*ND2 + c2);
        float2 v2 = *(const float2*)(p2b + (size_t)a2*ND2 + c2);
        float ox = w0*v0.x + w1*v1.x + w2*v2.x;
        float oy = w0*v0.y + w1*v1.y + w2*v2.y;
        s16x2 o; o[0] = f2bf(ox); o[1] = f2bf(oy);
        *(s16x2*)(xrow + (size_t)j*NCIN + ND1 + c2) = o;
    }
}

// ---------------------------------------------------------------------------
__global__ __launch_bounds__(256) void k_castw(
    const float* __restrict__ W1, const float* __restrict__ W2,
    unsigned short* __restrict__ Wb)
{
    int i = blockIdx.x * 256 + threadIdx.x;
    if (i < NC1*NCIN)                Wb[i] = (unsigned short)f2bf(W1[i]);
    else if (i < NC1*NCIN + NC2*NC1) Wb[i] = (unsigned short)f2bf(W2[i - NC1*NCIN]);
}

__global__ __launch_bounds__(256) void k_zero(float* __restrict__ p) {
    p[blockIdx.x * 256 + threadIdx.x] = 0.f;
}

// ---------------------------------------------------------------------------
// GEMM1 (MFMA): y1[b][n][o] = bf16( b1[o] + sum_c W1[o][c]*x[b][n][c] )
// Block tile 128o x 128n, 4 waves (2o x 2n), wave tile 64x64. Direct-global.
// ---------------------------------------------------------------------------
__global__ __launch_bounds__(256) void k_gemm1(
    const unsigned short* __restrict__ Xb, const unsigned short* __restrict__ W1b,
    const float* __restrict__ b1, unsigned short* __restrict__ y1)
{
    const int t   = threadIdx.x;
    const int w   = t >> 6;
    const int wo  = w >> 1, wn = w & 1;
    const int l   = t & 63;
    const int l16 = l & 15, lk = l >> 4;
    const int n1  = blockIdx.x * 128 + wn * 64;
    const int o1  = blockIdx.y * 128 + wo * 64;
    const int b   = blockIdx.z;

    const unsigned short* xrow = Xb + (size_t)b * NN * NCIN;
    f32x4 acc[4][4] = {};

    const unsigned short* ap[4];
    const unsigned short* bp[4];
    #pragma unroll
    for (int m = 0; m < 4; ++m)
        ap[m] = W1b + (size_t)(o1 + m*16 + l16) * NCIN + lk*8;
    #pragma unroll
    for (int nn = 0; nn < 4; ++nn)
        bp[nn] = xrow + (size_t)(n1 + nn*16 + l16) * NCIN + lk*8;

    #pragma unroll 2
    for (int k0 = 0; k0 < NCIN; k0 += 32) {
        s16x8 af[4], bf[4];
        #pragma unroll
        for (int m = 0; m < 4; ++m) af[m] = *(const s16x8*)(ap[m] + k0);
        #pragma unroll
        for (int nn = 0; nn < 4; ++nn) bf[nn] = *(const s16x8*)(bp[nn] + k0);
        #pragma unroll
        for (int m = 0; m < 4; ++m)
            #pragma unroll
            for (int nn = 0; nn < 4; ++nn)
                acc[m][nn] = __builtin_amdgcn_mfma_f32_16x16x32_bf16(
                    af[m], bf[nn], acc[m][nn], 0, 0, 0);
    }

    unsigned short* yb = y1 + (size_t)b * NN * NC1;
    #pragma unroll
    for (int m = 0; m < 4; ++m) {
        f32x4 bias = *(const f32x4*)(b1 + o1 + m*16 + lk*4);
        #pragma unroll
        for (int nn = 0; nn < 4; ++nn) {
            int nidx = n1 + nn*16 + l16;
            f32x4 v = acc[m][nn] + bias;
            s16x4 o;
            o[0] = f2bf(v[0]); o[1] = f2bf(v[1]); o[2] = f2bf(v[2]); o[3] = f2bf(v[3]);
            *(s16x4*)(yb + (size_t)nidx*NC1 + o1 + m*16 + lk*4) = o;
        }
    }
}

// ---------------------------------------------------------------------------
// Stats over n for y1 bf16 [b][n][256]: per-block partials + atomics.
// ---------------------------------------------------------------------------
__global__ __launch_bounds__(256) void k_stats1(
    const unsigned short* __restrict__ y1, float* __restrict__ S, float* __restrict__ S2)
{
    const int t = threadIdx.x;
    const int b = blockIdx.y;
    const int n0 = blockIdx.x * 256;
    const int c = t & 127, h = t >> 7;
    const unsigned short* p = y1 + ((size_t)(b*NN + n0 + h))*NC1 + c*2;
    float sl=0.f, sh=0.f, ql=0.f, qh=0.f;
    for (int r = 0; r < 128; ++r) {
        unsigned u = *(const unsigned*)(p + (size_t)(2*r)*NC1);
        float flo = bflo(u), fhi = bfhi(u);
        sl += flo; ql += flo*flo; sh += fhi; qh += fhi*fhi;
    }
    __shared__ float red[4][128];
    if (h) { red[0][c]=sl; red[1][c]=sh; red[2][c]=ql; red[3][c]=qh; }
    __syncthreads();
    if (!h) {
        sl += red[0][c]; sh += red[1][c]; ql += red[2][c]; qh += red[3][c];
        atomicAdd(&S [b*NC1 + 2*c],   sl);
        atomicAdd(&S [b*NC1 + 2*c+1], sh);
        atomicAdd(&S2[b*NC1 + 2*c],   ql);
        atomicAdd(&S2[b*NC1 + 2*c+1], qh);
    }
}

__global__ __launch_bounds__(256) void k_stats2(
    const unsigned short* __restrict__ y2, float* __restrict__ S, float* __restrict__ S2)
{
    const int t = threadIdx.x;
    const int b = blockIdx.y;
    const int n0 = blockIdx.x * 256;
    const int c = t & 63, h = t >> 6;
    const unsigned short* p = y2 + ((size_t)(b*NN + n0 + h))*NC2 + c*2;
    float sl=0.f, sh=0.f, ql=0.f, qh=0.f;
    for (int r = 0; r < 64; ++r) {
        unsigned u = *(const unsigned*)(p + (size_t)(4*r)*NC2);
        float flo = bflo(u), fhi = bfhi(u);
        sl += flo; ql += flo*flo; sh += fhi; qh += fhi*fhi;
    }
    __shared__ float red[3][4][64];
    if (h) { red[h-1][0][c]=sl; red[h-1][1][c]=sh; red[h-1][2][c]=ql; red[h-1][3][c]=qh; }
    __syncthreads();
    if (!h) {
        #pragma unroll
        for (int g = 0; g < 3; ++g) {
            sl += red[g][0][c]; sh += red[g][1][c];
            ql += red[g][2][c]; qh += red[g][3][c];
        }
        atomicAdd(&S [b*NC2 + 2*c],   sl);
        atomicAdd(&S [b*NC2 + 2*c+1], sh);
        atomicAdd(&S2[b*NC2 + 2*c],   ql);
        atomicAdd(&S2[b*NC2 + 2*c+1], qh);
    }
}

__global__ __launch_bounds__(256) void k_finstats(
    const float* __restrict__ S, const float* __restrict__ S2,
    float* __restrict__ mu, float* __restrict__ rs, int nent)
{
    int i = blockIdx.x * 256 + threadIdx.x;
    if (i < nent) {
        float m = S[i] * (1.0f/(float)NN);
        float var = S2[i] * (1.0f/(float)NN) - m*m;
        mu[i] = m;
        rs[i] = 1.0f / sqrtf(var + EPS_INORM);
    }
}

// ---------------------------------------------------------------------------
// Fold rs1 into W2 per batch: W2f[b][o][c] = bf16( W2[o][c] * rs1[b][c] )
// ---------------------------------------------------------------------------
__global__ __launch_bounds__(256) void k_foldw2(
    const unsigned short* __restrict__ W2b, const float* __restrict__ rs1,
    unsigned short* __restrict__ W2f)
{
    int i = blockIdx.x * 256 + threadIdx.x;   // over 8*128*256
    int b = i >> 15;
    int c = i & 255;
    float wv = bflo((unsigned)W2b[i & 32767] << 0);  // bf16 -> f32
    wv = __uint_as_float(((unsigned)W2b[i & 32767]) << 16);
    W2f[i] = (unsigned short)f2bf(wv * rs1[b*NC1 + c]);
}

// ---------------------------------------------------------------------------
// GEMM2 (MFMA): y2[b][n][o] = bf16( b2[o] + sum_c W2f[b][o][c]*max(y1-mu1,0) )
// Block tile 128o(full) x 128n, 4 waves (2o x 2n). y1 read exactly once.
// ---------------------------------------------------------------------------
__global__ __launch_bounds__(256) void k_gemm2(
    const unsigned short* __restrict__ y1, const unsigned short* __restrict__ W2f,
    const float* __restrict__ b2, const float* __restrict__ mu1,
    unsigned short* __restrict__ y2)
{
    const int t   = threadIdx.x;
    const int w   = t >> 6;
    const int wo  = w >> 1, wn = w & 1;
    const int l   = t & 63;
    const int l16 = l & 15, lk = l >> 4;
    const int n1  = blockIdx.x * 128 + wn * 64;
    const int o1  = wo * 64;
    const int b   = blockIdx.y;

    const unsigned short* yrow = y1 + (size_t)b * NN * NC1;
    const unsigned short* wrow = W2f + (size_t)b * NC2 * NC1;
    const float* mu = mu1 + b * NC1;
    f32x4 acc[4][4] = {};

    const unsigned short* ap[4];
    const unsigned short* bp[4];
    #pragma unroll
    for (int m = 0; m < 4; ++m)
        ap[m] = wrow + (size_t)(o1 + m*16 + l16) * NC1 + lk*8;
    #pragma unroll
    for (int nn = 0; nn < 4; ++nn)
        bp[nn] = yrow + (size_t)(n1 + nn*16 + l16) * NC1 + lk*8;

    #pragma unroll 2
    for (int k0 = 0; k0 < NC1; k0 += 32) {
        f32x4 m0 = *(const f32x4*)(mu + k0 + lk*8);
        f32x4 m1 = *(const f32x4*)(mu + k0 + lk*8 + 4);
        s16x8 af[4], bf[4];
        #pragma unroll
        for (int m = 0; m < 4; ++m) af[m] = *(const s16x8*)(ap[m] + k0);
        #pragma unroll
        for (int nn = 0; nn < 4; ++nn) {
            uint4 ru = *(const uint4*)(bp[nn] + k0);
            float z0 = fmaxf(bflo(ru.x) - m0[0], 0.f);
            float z1 = fmaxf(bfhi(ru.x) - m0[1], 0.f);
            float z2 = fmaxf(bflo(ru.y) - m0[2], 0.f);
            float z3 = fmaxf(bfhi(ru.y) - m0[3], 0.f);
            float z4 = fmaxf(bflo(ru.z) - m1[0], 0.f);
            float z5 = fmaxf(bfhi(ru.z) - m1[1], 0.f);
            float z6 = fmaxf(bflo(ru.w) - m1[2], 0.f);
            float z7 = fmaxf(bfhi(ru.w) - m1[3], 0.f);
            union { uint4 u; s16x8 s; } cv;
            cv.u.x = pkbf(z0, z1); cv.u.y = pkbf(z2, z3);
            cv.u.z = pkbf(z4, z5); cv.u.w = pkbf(z6, z7);
            bf[nn] = cv.s;
        }
        #pragma unroll
        for (int m = 0; m < 4; ++m)
            #pragma unroll
            for (int nn = 0; nn < 4; ++nn)
                acc[m][nn] = __builtin_amdgcn_mfma_f32_16x16x32_bf16(
                    af[m], bf[nn], acc[m][nn], 0, 0, 0);
    }

    unsigned short* yb = y2 + (size_t)b * NN * NC2;
    #pragma unroll
    for (int m = 0; m < 4; ++m) {
        f32x4 bias = *(const f32x4*)(b2 + o1 + m*16 + lk*4);
        #pragma unroll
        for (int nn = 0; nn < 4; ++nn) {
            int nidx = n1 + nn*16 + l16;
            f32x4 v = acc[m][nn] + bias;
            s16x4 o;
            o[0] = f2bf(v[0]); o[1] = f2bf(v[1]); o[2] = f2bf(v[2]); o[3] = f2bf(v[3]);
            *(s16x4*)(yb + (size_t)nidx*NC2 + o1 + m*16 + lk*4) = o;
        }
    }
}

// ---------------------------------------------------------------------------
// Final: out[b][n][o] = relu((y2[b][n][o]-mu2[o])*rs2[o])  f32
// ---------------------------------------------------------------------------
__global__ __launch_bounds__(256) void k_final(
    const unsigned short* __restrict__ y2, const float* __restrict__ mu2,
    const float* __restrict__ rs2, float* __restrict__ out)
{
    const int total4 = NB * NN * NC2 / 4;
    const int perb4  = NN * NC2 / 4;
    for (int i = blockIdx.x * 256 + threadIdx.x; i < total4; i += gridDim.x * 256) {
        int b  = i / perb4;
        int c4 = (i & 31) * 4;
        uint2 u = *(const uint2*)(y2 + (size_t)i*4);
        f32x4 m = *(const f32x4*)(mu2 + b*NC2 + c4);
        f32x4 r = *(const f32x4*)(rs2 + b*NC2 + c4);
        f32x4 o;
        o[0] = fmaxf(0.f, (bflo(u.x) - m[0]) * r[0]);
        o[1] = fmaxf(0.f, (bfhi(u.x) - m[1]) * r[1]);
        o[2] = fmaxf(0.f, (bflo(u.y) - m[2]) * r[2]);
        o[3] = fmaxf(0.f, (bfhi(u.y) - m[3]) * r[3]);
        *(f32x4*)(out + (size_t)i*4) = o;
    }
}

// ---------------------------------------------------------------------------
extern "C" void kernel_launch(void* const* d_in, const int* in_sizes, int n_in,
                              void* d_out, int out_size, void* d_ws, size_t ws_size,
                              hipStream_t stream) {
    const float* xyz1    = (const float*)d_in[0];
    const float* xyz2    = (const float*)d_in[1];
    const float* points1 = (const float*)d_in[2];
    const float* points2 = (const float*)d_in[3];
    const float* W1      = (const float*)d_in[4];
    const float* b1      = (const float*)d_in[5];
    const float* W2      = (const float*)d_in[6];
    const float* b2      = (const float*)d_in[7];
    float* out = (float*)d_out;

    char* ws = (char*)d_ws;
    unsigned short* xb  = (unsigned short*)(ws);             // 50,331,648 B
    unsigned short* y1b = (unsigned short*)(ws + 50331648);  // 33,554,432 B
    unsigned short* y2b = (unsigned short*)(ws + 83886080);  // 16,777,216 B
    unsigned short* Wb  = (unsigned short*)(ws + 100663296); // 262,144 B
    unsigned short* W2f = (unsigned short*)(ws + 100925440); // 524,288 B
    float* accb = (float*)(ws + 101449728);                  // 6144 f (zeroed)
    float* S1a = accb;
    float* S2a = accb + 2048;
    float* T1a = accb + 4096;
    float* T2a = accb + 5120;
    float* prm = (float*)(ws + 101474304);
    float* mu1 = prm;
    float* rs1 = prm + 2048;
    float* mu2 = prm + 4096;
    float* rs2 = prm + 5120;
    unsigned short* W2b = Wb + NC1*NCIN;

    k_zero<<<24, 256, 0, stream>>>(accb);
    k_castw<<<512, 256, 0, stream>>>(W1, W2, Wb);
    k_knn_interp<<<dim3(NN/64, NB), 256, 0, stream>>>(xyz1, xyz2, points1, points2, xb);
    k_gemm1<<<dim3(NN/128, NC1/128, NB), 256, 0, stream>>>(xb, Wb, b1, y1b);
    k_stats1<<<dim3(NN/256, NB), 256, 0, stream>>>(y1b, S1a, S2a);
    k_finstats<<<8, 256, 0, stream>>>(S1a, S2a, mu1, rs1, NB*NC1);
    k_foldw2<<<1024, 256, 0, stream>>>(W2b, rs1, W2f);
    k_gemm2<<<dim3(NN/128, NB), 256, 0, stream>>>(y1b, W2f, b2, mu1, y2b);
    k_stats2<<<dim3(NN/256, NB), 256, 0, stream>>>(y2b, T1a, T2a);
    k_finstats<<<4, 256, 0, stream>>>(T1a, T2a, mu2, rs2, NB*NC2);
    k_final<<<2048, 256, 0, stream>>>(y2b, mu2, rs2, out);
}

// Round 5
// 267.950 us; speedup vs baseline: 2.2923x; 1.1240x over previous
//
#include <hip/hip_runtime.h>
#include <math.h>

#define NB   8
#define NN   8192
#define NS   2048
#define ND1  128
#define ND2  256
#define NCIN 384
#define NC1  256
#define NC2  128

#define EPS_ITP 1e-8f
#define EPS_INORM 1e-5f

typedef float f32x4 __attribute__((ext_vector_type(4)));
typedef short s16x8 __attribute__((ext_vector_type(8)));
typedef short s16x4 __attribute__((ext_vector_type(4)));
typedef short s16x2 __attribute__((ext_vector_type(2)));

// RNE float->bf16 (finite inputs)
static __device__ __forceinline__ short f2bf(float f) {
    unsigned u = __float_as_uint(f);
    unsigned r = (u + 0x7FFFu + ((u >> 16) & 1u)) >> 16;
    return (short)r;
}
static __device__ __forceinline__ float bflo(unsigned u) { return __uint_as_float(u << 16); }
static __device__ __forceinline__ float bfhi(unsigned u) { return __uint_as_float(u & 0xFFFF0000u); }
// pack 2 f32 -> 2 bf16 in one u32 (lo=a, hi=b)
static __device__ __forceinline__ unsigned pkbf(float a, float b) {
    unsigned r;
    asm("v_cvt_pk_bf16_f32 %0, %1, %2" : "=v"(r) : "v"(a), "v"(b));
    return r;
}

// ---------------------------------------------------------------------------
// Kernel 1: 3-NN + inverse-distance interp + concat -> x bf16 [B][N][384]
// 64 points/block, 4 slices/point scan 512 candidates each, LDS merge.
// Scan is BRANCHLESS: score d' = q2 - 2*p.q via 3 FMA from packed LDS
// (-2qx,-2qy,-2qz,q2); top-3 values via min/med3, indices via cndmask.
// LDS 38912B -> 4 blocks/CU (16 waves).
// ---------------------------------------------------------------------------
__global__ __launch_bounds__(256) void k_knn_interp(
    const float* __restrict__ xyz1, const float* __restrict__ xyz2,
    const float* __restrict__ points1, const float* __restrict__ points2,
    unsigned short* __restrict__ xb)
{
    __shared__ float q[NS * 4];        // 32768 B
    __shared__ float sd[4][64][3];     // 3072 B
    __shared__ int   sl[4][64][3];     // 3072 B
    // sw/si overlay sd/sl (dead after merge)
    float (*sw)[3] = (float(*)[3])&sd[0][0][0];
    int   (*si)[3] = (int  (*)[3])&sl[0][0][0];

    const int t  = threadIdx.x;
    const int b  = blockIdx.y;
    const int n0 = blockIdx.x * 64;

    const float* xz2 = xyz2 + b * NS * 3;
    for (int e = t; e < NS * 3; e += 256)
        q[(e / 3) * 4 + (e % 3)] = xz2[e];
    __syncthreads();
    for (int s = t; s < NS; s += 256) {
        float qx = q[s*4+0], qy = q[s*4+1], qz = q[s*4+2];
        q[s*4+3] = qx*qx + qy*qy + qz*qz;
        q[s*4+0] = -2.0f*qx; q[s*4+1] = -2.0f*qy; q[s*4+2] = -2.0f*qz;
    }
    __syncthreads();

    const int p  = t & 63;
    const int ss = t >> 6;
    const int n  = n0 + p;
    const float px = xyz1[(b*NN + n)*3 + 0];
    const float py = xyz1[(b*NN + n)*3 + 1];
    const float pz = xyz1[(b*NN + n)*3 + 2];
    const float p2 = px*px + py*py + pz*pz;

    // slice-local top-3 on d' = q2 - 2 p.q  (p2-shift invariant selection)
    float d0 = 3.4e38f, d1 = 3.4e38f, d2v = 3.4e38f;
    int   i0 = 0, i1 = 0, i2 = 0;
    const int sbeg = ss * (NS/4);
    const int send = sbeg + (NS/4);
    #pragma unroll 4
    for (int s = sbeg; s < send; ++s) {
        float4 qq = *(const float4*)&q[s*4];
        float dp = fmaf(px, qq.x, fmaf(py, qq.y, fmaf(pz, qq.z, qq.w)));
        bool c0 = dp < d0, c1 = dp < d1, c2 = dp < d2v;
        int ni2 = c1 ? i1 : (c2 ? s : i2);
        int ni1 = c0 ? i0 : (c1 ? s : i1);
        int ni0 = c0 ? s  : i0;
        i2 = ni2; i1 = ni1; i0 = ni0;
        float nd2 = __builtin_amdgcn_fmed3f(d1, d2v, dp);
        float nd1 = __builtin_amdgcn_fmed3f(d0, d1, dp);
        float nd0 = fminf(d0, dp);
        d2v = nd2; d1 = nd1; d0 = nd0;
    }
    sd[ss][p][0] = d0; sd[ss][p][1] = d1; sd[ss][p][2] = d2v;
    sl[ss][p][0] = i0; sl[ss][p][1] = i1; sl[ss][p][2] = i2;
    __syncthreads();

    // merge 4 slices' top-3 (12 entries) -> global top-3; t<64 only.
    float w0r=0.f, w1r=0.f, w2r=0.f; int b0r=0, b1r=0, b2r=0;
    if (t < 64) {
        float dv[12]; int iv[12];
        #pragma unroll
        for (int m = 0; m < 4; ++m)
            #pragma unroll
            for (int k = 0; k < 3; ++k) {
                dv[m*3+k] = sd[m][t][k];
                iv[m*3+k] = sl[m][t][k];
            }
        float bd[3]; int bi[3];
        #pragma unroll
        for (int r = 0; r < 3; ++r) {
            int best = 0; float bv = dv[0];
            #pragma unroll
            for (int m = 1; m < 12; ++m)
                if (dv[m] < bv) { bv = dv[m]; best = m; }
            bd[r] = bv; bi[r] = iv[best]; dv[best] = 3.4e38f;
        }
        // actual distances: d = d' + p2 (p2 of point t is this thread's p2)
        float r0 = 1.0f/(bd[0]+p2+EPS_ITP);
        float r1 = 1.0f/(bd[1]+p2+EPS_ITP);
        float r2 = 1.0f/(bd[2]+p2+EPS_ITP);
        float rsum = r0 + r1 + r2;
        w0r = r0/rsum; w1r = r1/rsum; w2r = r2/rsum;
        b0r = bi[0]; b1r = bi[1]; b2r = bi[2];
    }
    __syncthreads();   // sd/sl reads done; safe to overlay
    if (t < 64) {
        sw[t][0] = w0r; sw[t][1] = w1r; sw[t][2] = w2r;
        si[t][0] = b0r; si[t][1] = b1r; si[t][2] = b2r;
    }
    __syncthreads();

    const float* p1 = points1 + (size_t)(b*NN + n0) * ND1;
    unsigned short* xrow = xb + (size_t)(b*NN + n0) * NCIN;
    #pragma unroll
    for (int i = 0; i < 8; ++i) {
        int e   = t + i*256;
        int row = e >> 5;
        int c4  = (e & 31) << 2;
        float4 v = *(const float4*)(p1 + (size_t)row*ND1 + c4);
        s16x4 o;
        o[0] = f2bf(v.x); o[1] = f2bf(v.y); o[2] = f2bf(v.z); o[3] = f2bf(v.w);
        *(s16x4*)(xrow + (size_t)row*NCIN + c4) = o;
    }
    const float* p2b = points2 + (size_t)b*NS*ND2;
    const int half = t >> 7;
    const int c2   = (t & 127) * 2;
    for (int j2 = 0; j2 < 32; ++j2) {
        int j = j2*2 + half;
        float w0 = sw[j][0], w1 = sw[j][1], w2 = sw[j][2];
        int   a0 = si[j][0], a1 = si[j][1], a2 = si[j][2];
        float2 v0 = *(const float2*)(p2b + (size_t)a0*ND2 + c2);
        float2 v1 = *(const float2*)(p2b + (size_t)a1*ND2 + c2);
        float2 v2 = *(const float2*)(p2b + (size_t)a2*ND2 + c2);
        float ox = w0*v0.x + w1*v1.x + w2*v2.x;
        float oy = w0*v0.y + w1*v1.y + w2*v2.y;
        s16x2 o; o[0] = f2bf(ox); o[1] = f2bf(oy);
        *(s16x2*)(xrow + (size_t)j*NCIN + ND1 + c2) = o;
    }
}

// ---------------------------------------------------------------------------
__global__ __launch_bounds__(256) void k_castw(
    const float* __restrict__ W1, const float* __restrict__ W2,
    unsigned short* __restrict__ Wb)
{
    int i = blockIdx.x * 256 + threadIdx.x;
    if (i < NC1*NCIN)                Wb[i] = (unsigned short)f2bf(W1[i]);
    else if (i < NC1*NCIN + NC2*NC1) Wb[i] = (unsigned short)f2bf(W2[i - NC1*NCIN]);
}

__global__ __launch_bounds__(256) void k_zero(float* __restrict__ p) {
    p[blockIdx.x * 256 + threadIdx.x] = 0.f;
}

// ---------------------------------------------------------------------------
// GEMM1 (MFMA): y1[b][n][o] = bf16( b1[o] + sum_c W1[o][c]*x[b][n][c] )
// Block tile 128o x 128n, 4 waves (2o x 2n), wave tile 64x64. Direct-global.
// ---------------------------------------------------------------------------
__global__ __launch_bounds__(256) void k_gemm1(
    const unsigned short* __restrict__ Xb, const unsigned short* __restrict__ W1b,
    const float* __restrict__ b1, unsigned short* __restrict__ y1)
{
    const int t   = threadIdx.x;
    const int w   = t >> 6;
    const int wo  = w >> 1, wn = w & 1;
    const int l   = t & 63;
    const int l16 = l & 15, lk = l >> 4;
    const int n1  = blockIdx.x * 128 + wn * 64;
    const int o1  = blockIdx.y * 128 + wo * 64;
    const int b   = blockIdx.z;

    const unsigned short* xrow = Xb + (size_t)b * NN * NCIN;
    f32x4 acc[4][4] = {};

    const unsigned short* ap[4];
    const unsigned short* bp[4];
    #pragma unroll
    for (int m = 0; m < 4; ++m)
        ap[m] = W1b + (size_t)(o1 + m*16 + l16) * NCIN + lk*8;
    #pragma unroll
    for (int nn = 0; nn < 4; ++nn)
        bp[nn] = xrow + (size_t)(n1 + nn*16 + l16) * NCIN + lk*8;

    #pragma unroll 2
    for (int k0 = 0; k0 < NCIN; k0 += 32) {
        s16x8 af[4], bf[4];
        #pragma unroll
        for (int m = 0; m < 4; ++m) af[m] = *(const s16x8*)(ap[m] + k0);
        #pragma unroll
        for (int nn = 0; nn < 4; ++nn) bf[nn] = *(const s16x8*)(bp[nn] + k0);
        #pragma unroll
        for (int m = 0; m < 4; ++m)
            #pragma unroll
            for (int nn = 0; nn < 4; ++nn)
                acc[m][nn] = __builtin_amdgcn_mfma_f32_16x16x32_bf16(
                    af[m], bf[nn], acc[m][nn], 0, 0, 0);
    }

    unsigned short* yb = y1 + (size_t)b * NN * NC1;
    #pragma unroll
    for (int m = 0; m < 4; ++m) {
        f32x4 bias = *(const f32x4*)(b1 + o1 + m*16 + lk*4);
        #pragma unroll
        for (int nn = 0; nn < 4; ++nn) {
            int nidx = n1 + nn*16 + l16;
            f32x4 v = acc[m][nn] + bias;
            s16x4 o;
            o[0] = f2bf(v[0]); o[1] = f2bf(v[1]); o[2] = f2bf(v[2]); o[3] = f2bf(v[3]);
            *(s16x4*)(yb + (size_t)nidx*NC1 + o1 + m*16 + lk*4) = o;
        }
    }
}

// ---------------------------------------------------------------------------
// Stats over n for y1 bf16 [b][n][256]: per-block partials + atomics.
// ---------------------------------------------------------------------------
__global__ __launch_bounds__(256) void k_stats1(
    const unsigned short* __restrict__ y1, float* __restrict__ S, float* __restrict__ S2)
{
    const int t = threadIdx.x;
    const int b = blockIdx.y;
    const int n0 = blockIdx.x * 256;
    const int c = t & 127, h = t >> 7;
    const unsigned short* p = y1 + ((size_t)(b*NN + n0 + h))*NC1 + c*2;
    float sl=0.f, sh=0.f, ql=0.f, qh=0.f;
    for (int r = 0; r < 128; ++r) {
        unsigned u = *(const unsigned*)(p + (size_t)(2*r)*NC1);
        float flo = bflo(u), fhi = bfhi(u);
        sl += flo; ql += flo*flo; sh += fhi; qh += fhi*fhi;
    }
    __shared__ float red[4][128];
    if (h) { red[0][c]=sl; red[1][c]=sh; red[2][c]=ql; red[3][c]=qh; }
    __syncthreads();
    if (!h) {
        sl += red[0][c]; sh += red[1][c]; ql += red[2][c]; qh += red[3][c];
        atomicAdd(&S [b*NC1 + 2*c],   sl);
        atomicAdd(&S [b*NC1 + 2*c+1], sh);
        atomicAdd(&S2[b*NC1 + 2*c],   ql);
        atomicAdd(&S2[b*NC1 + 2*c+1], qh);
    }
}

__global__ __launch_bounds__(256) void k_stats2(
    const unsigned short* __restrict__ y2, float* __restrict__ S, float* __restrict__ S2)
{
    const int t = threadIdx.x;
    const int b = blockIdx.y;
    const int n0 = blockIdx.x * 256;
    const int c = t & 63, h = t >> 6;
    const unsigned short* p = y2 + ((size_t)(b*NN + n0 + h))*NC2 + c*2;
    float sl=0.f, sh=0.f, ql=0.f, qh=0.f;
    for (int r = 0; r < 64; ++r) {
        unsigned u = *(const unsigned*)(p + (size_t)(4*r)*NC2);
        float flo = bflo(u), fhi = bfhi(u);
        sl += flo; ql += flo*flo; sh += fhi; qh += fhi*fhi;
    }
    __shared__ float red[3][4][64];
    if (h) { red[h-1][0][c]=sl; red[h-1][1][c]=sh; red[h-1][2][c]=ql; red[h-1][3][c]=qh; }
    __syncthreads();
    if (!h) {
        #pragma unroll
        for (int g = 0; g < 3; ++g) {
            sl += red[g][0][c]; sh += red[g][1][c];
            ql += red[g][2][c]; qh += red[g][3][c];
        }
        atomicAdd(&S [b*NC2 + 2*c],   sl);
        atomicAdd(&S [b*NC2 + 2*c+1], sh);
        atomicAdd(&S2[b*NC2 + 2*c],   ql);
        atomicAdd(&S2[b*NC2 + 2*c+1], qh);
    }
}

__global__ __launch_bounds__(256) void k_finstats(
    const float* __restrict__ S, const float* __restrict__ S2,
    float* __restrict__ mu, float* __restrict__ rs, int nent)
{
    int i = blockIdx.x * 256 + threadIdx.x;
    if (i < nent) {
        float m = S[i] * (1.0f/(float)NN);
        float var = S2[i] * (1.0f/(float)NN) - m*m;
        mu[i] = m;
        rs[i] = 1.0f / sqrtf(var + EPS_INORM);
    }
}

// ---------------------------------------------------------------------------
// Fold rs1 into W2 per batch: W2f[b][o][c] = bf16( W2[o][c] * rs1[b][c] )
// ---------------------------------------------------------------------------
__global__ __launch_bounds__(256) void k_foldw2(
    const unsigned short* __restrict__ W2b, const float* __restrict__ rs1,
    unsigned short* __restrict__ W2f)
{
    int i = blockIdx.x * 256 + threadIdx.x;   // over 8*128*256
    int b = i >> 15;
    int c = i & 255;
    float wv = __uint_as_float(((unsigned)W2b[i & 32767]) << 16);
    W2f[i] = (unsigned short)f2bf(wv * rs1[b*NC1 + c]);
}

// ---------------------------------------------------------------------------
// GEMM2 (MFMA): y2[b][n][o] = bf16( b2[o] + sum_c W2f[b][o][c]*max(y1-mu1,0) )
// Block tile 128o(full) x 128n, 4 waves (2o x 2n). y1 read exactly once.
// ---------------------------------------------------------------------------
__global__ __launch_bounds__(256) void k_gemm2(
    const unsigned short* __restrict__ y1, const unsigned short* __restrict__ W2f,
    const float* __restrict__ b2, const float* __restrict__ mu1,
    unsigned short* __restrict__ y2)
{
    const int t   = threadIdx.x;
    const int w   = t >> 6;
    const int wo  = w >> 1, wn = w & 1;
    const int l   = t & 63;
    const int l16 = l & 15, lk = l >> 4;
    const int n1  = blockIdx.x * 128 + wn * 64;
    const int o1  = wo * 64;
    const int b   = blockIdx.y;

    const unsigned short* yrow = y1 + (size_t)b * NN * NC1;
    const unsigned short* wrow = W2f + (size_t)b * NC2 * NC1;
    const float* mu = mu1 + b * NC1;
    f32x4 acc[4][4] = {};

    const unsigned short* ap[4];
    const unsigned short* bp[4];
    #pragma unroll
    for (int m = 0; m < 4; ++m)
        ap[m] = wrow + (size_t)(o1 + m*16 + l16) * NC1 + lk*8;
    #pragma unroll
    for (int nn = 0; nn < 4; ++nn)
        bp[nn] = yrow + (size_t)(n1 + nn*16 + l16) * NC1 + lk*8;

    #pragma unroll 2
    for (int k0 = 0; k0 < NC1; k0 += 32) {
        f32x4 m0 = *(const f32x4*)(mu + k0 + lk*8);
        f32x4 m1 = *(const f32x4*)(mu + k0 + lk*8 + 4);
        s16x8 af[4], bf[4];
        #pragma unroll
        for (int m = 0; m < 4; ++m) af[m] = *(const s16x8*)(ap[m] + k0);
        #pragma unroll
        for (int nn = 0; nn < 4; ++nn) {
            uint4 ru = *(const uint4*)(bp[nn] + k0);
            float z0 = fmaxf(bflo(ru.x) - m0[0], 0.f);
            float z1 = fmaxf(bfhi(ru.x) - m0[1], 0.f);
            float z2 = fmaxf(bflo(ru.y) - m0[2], 0.f);
            float z3 = fmaxf(bfhi(ru.y) - m0[3], 0.f);
            float z4 = fmaxf(bflo(ru.z) - m1[0], 0.f);
            float z5 = fmaxf(bfhi(ru.z) - m1[1], 0.f);
            float z6 = fmaxf(bflo(ru.w) - m1[2], 0.f);
            float z7 = fmaxf(bfhi(ru.w) - m1[3], 0.f);
            union { uint4 u; s16x8 s; } cv;
            cv.u.x = pkbf(z0, z1); cv.u.y = pkbf(z2, z3);
            cv.u.z = pkbf(z4, z5); cv.u.w = pkbf(z6, z7);
            bf[nn] = cv.s;
        }
        #pragma unroll
        for (int m = 0; m < 4; ++m)
            #pragma unroll
            for (int nn = 0; nn < 4; ++nn)
                acc[m][nn] = __builtin_amdgcn_mfma_f32_16x16x32_bf16(
                    af[m], bf[nn], acc[m][nn], 0, 0, 0);
    }

    unsigned short* yb = y2 + (size_t)b * NN * NC2;
    #pragma unroll
    for (int m = 0; m < 4; ++m) {
        f32x4 bias = *(const f32x4*)(b2 + o1 + m*16 + lk*4);
        #pragma unroll
        for (int nn = 0; nn < 4; ++nn) {
            int nidx = n1 + nn*16 + l16;
            f32x4 v = acc[m][nn] + bias;
            s16x4 o;
            o[0] = f2bf(v[0]); o[1] = f2bf(v[1]); o[2] = f2bf(v[2]); o[3] = f2bf(v[3]);
            *(s16x4*)(yb + (size_t)nidx*NC2 + o1 + m*16 + lk*4) = o;
        }
    }
}

// ---------------------------------------------------------------------------
// Final: out[b][n][o] = relu((y2[b][n][o]-mu2[o])*rs2[o])  f32
// ---------------------------------------------------------------------------
__global__ __launch_bounds__(256) void k_final(
    const unsigned short* __restrict__ y2, const float* __restrict__ mu2,
    const float* __restrict__ rs2, float* __restrict__ out)
{
    const int total4 = NB * NN * NC2 / 4;
    const int perb4  = NN * NC2 / 4;
    for (int i = blockIdx.x * 256 + threadIdx.x; i < total4; i += gridDim.x * 256) {
        int b  = i / perb4;
        int c4 = (i & 31) * 4;
        uint2 u = *(const uint2*)(y2 + (size_t)i*4);
        f32x4 m = *(const f32x4*)(mu2 + b*NC2 + c4);
        f32x4 r = *(const f32x4*)(rs2 + b*NC2 + c4);
        f32x4 o;
        o[0] = fmaxf(0.f, (bflo(u.x) - m[0]) * r[0]);
        o[1] = fmaxf(0.f, (bfhi(u.x) - m[1]) * r[1]);
        o[2] = fmaxf(0.f, (bflo(u.y) - m[2]) * r[2]);
        o[3] = fmaxf(0.f, (bfhi(u.y) - m[3]) * r[3]);
        *(f32x4*)(out + (size_t)i*4) = o;
    }
}

// ---------------------------------------------------------------------------
extern "C" void kernel_launch(void* const* d_in, const int* in_sizes, int n_in,
                              void* d_out, int out_size, void* d_ws, size_t ws_size,
                              hipStream_t stream) {
    const float* xyz1    = (const float*)d_in[0];
    const float* xyz2    = (const float*)d_in[1];
    const float* points1 = (const float*)d_in[2];
    const float* points2 = (const float*)d_in[3];
    const float* W1      = (const float*)d_in[4];
    const float* b1      = (const float*)d_in[5];
    const float* W2      = (const float*)d_in[6];
    const float* b2      = (const float*)d_in[7];
    float* out = (float*)d_out;

    char* ws = (char*)d_ws;
    unsigned short* xb  = (unsigned short*)(ws);             // 50,331,648 B
    unsigned short* y1b = (unsigned short*)(ws + 50331648);  // 33,554,432 B
    unsigned short* y2b = (unsigned short*)(ws + 83886080);  // 16,777,216 B
    unsigned short* Wb  = (unsigned short*)(ws + 100663296); // 262,144 B
    unsigned short* W2f = (unsigned short*)(ws + 100925440); // 524,288 B
    float* accb = (float*)(ws + 101449728);                  // 6144 f (zeroed)
    float* S1a = accb;
    float* S2a = accb + 2048;
    float* T1a = accb + 4096;
    float* T2a = accb + 5120;
    float* prm = (float*)(ws + 101474304);
    float* mu1 = prm;
    float* rs1 = prm + 2048;
    float* mu2 = prm + 4096;
    float* rs2 = prm + 5120;
    unsigned short* W2b = Wb + NC1*NCIN;

    k_zero<<<24, 256, 0, stream>>>(accb);
    k_castw<<<512, 256, 0, stream>>>(W1, W2, Wb);
    k_knn_interp<<<dim3(NN/64, NB), 256, 0, stream>>>(xyz1, xyz2, points1, points2, xb);
    k_gemm1<<<dim3(NN/128, NC1/128, NB), 256, 0, stream>>>(xb, Wb, b1, y1b);
    k_stats1<<<dim3(NN/256, NB), 256, 0, stream>>>(y1b, S1a, S2a);
    k_finstats<<<8, 256, 0, stream>>>(S1a, S2a, mu1, rs1, NB*NC1);
    k_foldw2<<<1024, 256, 0, stream>>>(W2b, rs1, W2f);
    k_gemm2<<<dim3(NN/128, NB), 256, 0, stream>>>(y1b, W2f, b2, mu1, y2b);
    k_stats2<<<dim3(NN/256, NB), 256, 0, stream>>>(y2b, T1a, T2a);
    k_finstats<<<4, 256, 0, stream>>>(T1a, T2a, mu2, rs2, NB*NC2);
    k_final<<<2048, 256, 0, stream>>>(y2b, mu2, rs2, out);
}